// Round 8
// baseline (915.323 us; speedup 1.0000x reference)
//
#include <hip/hip_runtime.h>

#define N_NODES 100000
#define N_EDGES 1600000

typedef __attribute__((ext_vector_type(8))) unsigned short ushort8v;

// ---- workspace layout (bytes) ----
#define OFF_G0    0UL            // g ping  [N,64] bf16 (o-phase uses [N,32])
#define OFF_G1    25600000UL     // g pong  [N,64] bf16
#define OFF_HS    51200000UL     // hs      [N,128] f32
#define OFF_CSR   102400000UL    // CSR src [E] u32 (per row: p-edges then n-edges)
#define OFF_RP    108800000UL    // rowptr [N] (+scan pad)
#define OFF_CNT   109300000UL    // packed deg<<16 | posdeg, [N] u32
#define OFF_D2O   110100000UL    // 1/clip(deg)     f32 [N]
#define OFF_D2P   110500000UL
#define OFF_D2N   110900000UL
#define OFF_RDO   111300000UL    // sqrt(clip(deg)) f32 [N]
#define OFF_RDP   111700000UL
#define OFF_RDN   112100000UL
#define OFF_DVO   112500000UL    // rsqrt(clip(deg)) f32 [N]
#define OFF_DVP   112900000UL
#define OFF_DVN   113300000UL
#define OFF_CURP  113700000UL    // fill cursors [N]
#define OFF_CURN  114100000UL
#define OFF_PART  114500000UL    // scan partials [392] int

__device__ __forceinline__ float bf2f(unsigned short h) {
    union { unsigned u; float f; } c; c.u = ((unsigned)h) << 16; return c.f;
}
__device__ __forceinline__ unsigned short f2bf(float x) {
    union { float f; unsigned u; } c; c.f = x;
    unsigned r = (c.u + 0x7FFFu + ((c.u >> 16) & 1u)) >> 16;
    return (unsigned short)r;
}

__global__ __launch_bounds__(256) void k_mask_deg(
    const int* __restrict__ src, const int* __restrict__ dst,
    const int* __restrict__ labels, unsigned int* __restrict__ cnt) {
    int e = blockIdx.x * 256 + threadIdx.x;
    int s = src[e], d = dst[e];
    unsigned int p = (labels[s] == labels[d]) ? 1u : 0u;
    atomicAdd(&cnt[d], 0x10000u + p);   // deg in hi16, posdeg in lo16
}

__global__ __launch_bounds__(256) void k_dinv(
    const unsigned int* __restrict__ cnt,
    float* __restrict__ d2o, float* __restrict__ d2p, float* __restrict__ d2n,
    float* __restrict__ rdo, float* __restrict__ rdp, float* __restrict__ rdn,
    float* __restrict__ dvo, float* __restrict__ dvp, float* __restrict__ dvn) {
    int v = blockIdx.x * 256 + threadIdx.x;
    if (v >= N_NODES) return;
    unsigned int c = cnt[v];
    int dg = (int)(c >> 16), pg = (int)(c & 0xFFFF), ng = dg - pg;
    float co = (float)max(dg, 1);
    float cp = (float)max(pg, 1);
    float cn = (float)max(ng, 1);
    d2o[v] = 1.f / co; rdo[v] = sqrtf(co); dvo[v] = rsqrtf(co);
    d2p[v] = 1.f / cp; rdp[v] = sqrtf(cp); dvp[v] = rsqrtf(cp);
    d2n[v] = 1.f / cn; rdn[v] = sqrtf(cn); dvn[v] = rsqrtf(cn);
}

// ---- exclusive prefix scan over deg (hi16 of cnt) ----
__global__ __launch_bounds__(256) void k_scan_a(
    const unsigned int* __restrict__ cnt, int n, int* __restrict__ out,
    int* __restrict__ partial) {
    __shared__ int tmp[256];
    int g = blockIdx.x * 256 + threadIdx.x;
    int v = (g < n) ? (int)(cnt[g] >> 16) : 0;
    tmp[threadIdx.x] = v;
    __syncthreads();
    for (int off = 1; off < 256; off <<= 1) {
        int t = (threadIdx.x >= off) ? tmp[threadIdx.x - off] : 0;
        __syncthreads();
        tmp[threadIdx.x] += t;
        __syncthreads();
    }
    out[g] = tmp[threadIdx.x] - v;   // exclusive
    if (threadIdx.x == 255) partial[blockIdx.x] = tmp[255];
}

__global__ __launch_bounds__(512) void k_scan_b(int* __restrict__ partial, int nb) {
    __shared__ int tmp[512];
    int v = (threadIdx.x < nb) ? partial[threadIdx.x] : 0;
    tmp[threadIdx.x] = v;
    __syncthreads();
    for (int off = 1; off < 512; off <<= 1) {
        int t = (threadIdx.x >= off) ? tmp[threadIdx.x - off] : 0;
        __syncthreads();
        tmp[threadIdx.x] += t;
        __syncthreads();
    }
    if (threadIdx.x < nb) partial[threadIdx.x] = tmp[threadIdx.x] - v;
}

// finalize rowptr + init fill cursors (p at row start, n after posdeg)
__global__ __launch_bounds__(256) void k_scan_c(
    int* __restrict__ out, const int* __restrict__ partial, int n,
    const unsigned int* __restrict__ cnt,
    int* __restrict__ curp, int* __restrict__ curn) {
    int g = blockIdx.x * 256 + threadIdx.x;
    if (g < n) {
        int v = out[g] + partial[blockIdx.x];
        out[g] = v;
        curp[g] = v;
        curn[g] = v + (int)(cnt[g] & 0xFFFF);
    }
}

__global__ __launch_bounds__(256) void k_fill(
    const int* __restrict__ src, const int* __restrict__ dst,
    const int* __restrict__ labels,
    int* __restrict__ curp, int* __restrict__ curn,
    unsigned int* __restrict__ csr) {
    int e = blockIdx.x * 256 + threadIdx.x;
    int s = src[e], d = dst[e];
    int* cur = (labels[s] == labels[d]) ? curp : curn;
    csr[atomicAdd(&cur[d], 1)] = (unsigned int)s;
}

// ---- phase inits: g = bf16(feat * dinv) ----
__global__ __launch_bounds__(256) void k_init_o(
    const float* __restrict__ feat, const float* __restrict__ dvo,
    unsigned short* __restrict__ g0, float* __restrict__ hs) {
    int idx = blockIdx.x * 256 + threadIdx.x;   // over N*32
    int v = idx >> 5, c = idx & 31;
    float x = feat[idx];
    g0[idx] = f2bf(x * dvo[v]);
    hs[v * 128 + c] = 0.5f * x;                 // THETAS[0][0]
}

__global__ __launch_bounds__(256) void k_init_pn(
    const float* __restrict__ feat, const float* __restrict__ dvp, const float* __restrict__ dvn,
    unsigned short* __restrict__ g0, float* __restrict__ hs) {
    int idx = blockIdx.x * 256 + threadIdx.x;   // over N*32
    int v = idx >> 5, c = idx & 31;
    float x = feat[idx];
    g0[v * 64 + c]      = f2bf(x * dvp[v]);
    g0[v * 64 + 32 + c] = f2bf(x * dvn[v]);
    hs[v * 128 + c]      = 0.5f * x;            // THETAS[0][0] (p head)
    hs[v * 128 + 64 + c] = 0.1f * x;            // THETAS[2][0] (n head)
}

// ---- o-hop: 1 node/wave64; 16 edge-slots x 4 lanes x ushort8 (16B/lane) ----
__global__ __launch_bounds__(256) void k_hop_o(
    const int* __restrict__ rp, const unsigned int* __restrict__ cnt,
    const unsigned int* __restrict__ csr,
    const unsigned short* __restrict__ g_old, unsigned short* __restrict__ g_new,
    const float* __restrict__ d2, const float* __restrict__ rd,
    float* __restrict__ hs, int colA, float cA, int colB, float cB) {
    int v = (blockIdx.x * 256 + threadIdx.x) >> 6;
    int lane = threadIdx.x & 63;
    int slot = lane >> 2, fl = lane & 3;        // 16 slots x 4 lanes
    int beg = rp[v];
    int end = beg + (int)(cnt[v] >> 16);
    const ushort8v* gp = reinterpret_cast<const ushort8v*>(g_old);  // row = 4 units
    float acc[8] = {0.f, 0.f, 0.f, 0.f, 0.f, 0.f, 0.f, 0.f};
    for (int i = beg + slot; i < end; i += 16) {
        int s = (int)csr[i];
        ushort8v h = gp[s * 4 + fl];
#pragma unroll
        for (int j = 0; j < 8; ++j) acc[j] += bf2f(h[j]);
    }
#pragma unroll
    for (int m = 4; m < 64; m <<= 1)
#pragma unroll
        for (int j = 0; j < 8; ++j) acc[j] += __shfl_xor(acc[j], m);
    if (slot == 0) {   // lanes 0..3, each owns 8 cols
        float dd = d2[v], rr = rd[v];
        ushort8v gh = gp[v * 4 + fl];
        float gn[8], fn[8];
        ushort8v go;
#pragma unroll
        for (int j = 0; j < 8; ++j) {
            gn[j] = bf2f(gh[j]) - acc[j] * dd;
            go[j] = f2bf(gn[j]);
            fn[j] = gn[j] * rr;
        }
        reinterpret_cast<ushort8v*>(g_new)[v * 4 + fl] = go;
        float4* hp = reinterpret_cast<float4*>(hs + v * 128 + colA + fl * 8);
        float4 h0 = hp[0], h1 = hp[1];
        h0.x += cA * fn[0]; h0.y += cA * fn[1]; h0.z += cA * fn[2]; h0.w += cA * fn[3];
        h1.x += cA * fn[4]; h1.y += cA * fn[5]; h1.z += cA * fn[6]; h1.w += cA * fn[7];
        hp[0] = h0; hp[1] = h1;
        if (colB >= 0) {
            float4* bp = reinterpret_cast<float4*>(hs + v * 128 + colB + fl * 8);
            bp[0] = make_float4(cB * fn[0], cB * fn[1], cB * fn[2], cB * fn[3]);
            bp[1] = make_float4(cB * fn[4], cB * fn[5], cB * fn[6], cB * fn[7]);
        }
    }
}

// ---- pn-hop: 1 node/wave64; split CSR (p-section then n-section) ----
__global__ __launch_bounds__(256) void k_hop_pn(
    const int* __restrict__ rp, const unsigned int* __restrict__ cnt,
    const unsigned int* __restrict__ csr,
    const unsigned short* __restrict__ g_old, unsigned short* __restrict__ g_new,
    const float* __restrict__ d2p, const float* __restrict__ d2n,
    const float* __restrict__ rdp, const float* __restrict__ rdn,
    float* __restrict__ hs,
    int colAp, float cAp, int colAn, float cAn,
    int colB, float cBp, float cBn) {
    int v = (blockIdx.x * 256 + threadIdx.x) >> 6;
    int lane = threadIdx.x & 63;
    int slot = lane >> 2, fl = lane & 3;
    unsigned int c = cnt[v];
    int beg = rp[v];
    int mid = beg + (int)(c & 0xFFFF);
    int end = beg + (int)(c >> 16);
    const ushort8v* gp = reinterpret_cast<const ushort8v*>(g_old);  // row = 8 units
    float accp[8] = {0.f, 0.f, 0.f, 0.f, 0.f, 0.f, 0.f, 0.f};
    float accn[8] = {0.f, 0.f, 0.f, 0.f, 0.f, 0.f, 0.f, 0.f};
    for (int i = beg + slot; i < mid; i += 16) {
        int s = (int)csr[i];
        ushort8v h = gp[s * 8 + fl];
#pragma unroll
        for (int j = 0; j < 8; ++j) accp[j] += bf2f(h[j]);
    }
    for (int i = mid + slot; i < end; i += 16) {
        int s = (int)csr[i];
        ushort8v h = gp[s * 8 + 4 + fl];
#pragma unroll
        for (int j = 0; j < 8; ++j) accn[j] += bf2f(h[j]);
    }
#pragma unroll
    for (int m = 4; m < 64; m <<= 1)
#pragma unroll
        for (int j = 0; j < 8; ++j) {
            accp[j] += __shfl_xor(accp[j], m);
            accn[j] += __shfl_xor(accn[j], m);
        }
    if (slot == 0) {        // p half, lanes 0..3
        float dd = d2p[v], rr = rdp[v];
        ushort8v gh = gp[v * 8 + fl];
        float gn[8], fn[8];
        ushort8v go;
#pragma unroll
        for (int j = 0; j < 8; ++j) {
            gn[j] = bf2f(gh[j]) - accp[j] * dd;
            go[j] = f2bf(gn[j]);
            fn[j] = gn[j] * rr;
        }
        reinterpret_cast<ushort8v*>(g_new)[v * 8 + fl] = go;
        float4* hp = reinterpret_cast<float4*>(hs + v * 128 + colAp + fl * 8);
        float4 h0 = hp[0], h1 = hp[1];
        h0.x += cAp * fn[0]; h0.y += cAp * fn[1]; h0.z += cAp * fn[2]; h0.w += cAp * fn[3];
        h1.x += cAp * fn[4]; h1.y += cAp * fn[5]; h1.z += cAp * fn[6]; h1.w += cAp * fn[7];
        hp[0] = h0; hp[1] = h1;
        if (colB >= 0) {
            float4* bp = reinterpret_cast<float4*>(hs + v * 128 + colB + fl * 8);
            bp[0] = make_float4(cBp * fn[0], cBp * fn[1], cBp * fn[2], cBp * fn[3]);
            bp[1] = make_float4(cBp * fn[4], cBp * fn[5], cBp * fn[6], cBp * fn[7]);
        }
    } else if (slot == 1) { // n half, lanes 4..7
        float dd = d2n[v], rr = rdn[v];
        ushort8v gh = gp[v * 8 + 4 + fl];
        float gn[8], fn[8];
        ushort8v go;
#pragma unroll
        for (int j = 0; j < 8; ++j) {
            gn[j] = bf2f(gh[j]) - accn[j] * dd;
            go[j] = f2bf(gn[j]);
            fn[j] = gn[j] * rr;
        }
        reinterpret_cast<ushort8v*>(g_new)[v * 8 + 4 + fl] = go;
        float4* hp = reinterpret_cast<float4*>(hs + v * 128 + colAn + fl * 8);
        float4 h0 = hp[0], h1 = hp[1];
        h0.x += cAn * fn[0]; h0.y += cAn * fn[1]; h0.z += cAn * fn[2]; h0.w += cAn * fn[3];
        h1.x += cAn * fn[4]; h1.y += cAn * fn[5]; h1.z += cAn * fn[6]; h1.w += cAn * fn[7];
        hp[0] = h0; hp[1] = h1;
        if (colB >= 0) {
            float4* bp = reinterpret_cast<float4*>(hs + v * 128 + colB + 64 + fl * 8);
            bp[0] = make_float4(cBn * fn[0], cBn * fn[1], cBn * fn[2], cBn * fn[3]);
            bp[1] = make_float4(cBn * fn[4], cBn * fn[5], cBn * fn[6], cBn * fn[7]);
        }
    }
}

// ---- GEMM: out[N,64] = act(X[N,KDIM] @ W[KDIM,64] + b) ----
template <int KDIM, bool RELU>
__global__ __launch_bounds__(256) void k_gemm(
    const float* __restrict__ X, const float* __restrict__ W,
    const float* __restrict__ bias, float* __restrict__ out, int nrows) {
    constexpr int SXP = KDIM + 4;
    __shared__ float sW[KDIM * 64];
    __shared__ float sX[64 * SXP];
    int tid = threadIdx.x;
    int rowbase = blockIdx.x * 64;

    for (int i = tid; i < KDIM * 16; i += 256)
        reinterpret_cast<float4*>(sW)[i] = reinterpret_cast<const float4*>(W)[i];

    constexpr int QF4 = KDIM / 4;
    constexpr int RPP = 256 / QF4;
    int q = tid & (QF4 - 1);
    int rloc = tid / QF4;
#pragma unroll
    for (int pass = 0; pass < 64 / RPP; ++pass) {
        int r = rloc + pass * RPP;
        int rg = rowbase + r;
        float4 v = make_float4(0.f, 0.f, 0.f, 0.f);
        if (rg < nrows) v = reinterpret_cast<const float4*>(X + (size_t)rg * KDIM)[q];
        float* dst = sX + r * SXP + q * 4;
        dst[0] = v.x; dst[1] = v.y; dst[2] = v.z; dst[3] = v.w;
    }
    __syncthreads();

    int c0 = (tid & 15) * 4;
    int r0 = (tid >> 4) * 4;
    float4 bv = reinterpret_cast<const float4*>(bias)[tid & 15];
    float4 acc0 = bv, acc1 = bv, acc2 = bv, acc3 = bv;

#pragma unroll 4
    for (int k4 = 0; k4 < KDIM / 4; ++k4) {
        int k = k4 * 4;
        float4 x0 = *reinterpret_cast<const float4*>(sX + (r0 + 0) * SXP + k);
        float4 x1 = *reinterpret_cast<const float4*>(sX + (r0 + 1) * SXP + k);
        float4 x2 = *reinterpret_cast<const float4*>(sX + (r0 + 2) * SXP + k);
        float4 x3 = *reinterpret_cast<const float4*>(sX + (r0 + 3) * SXP + k);
        float4 w0 = *reinterpret_cast<const float4*>(sW + (k + 0) * 64 + c0);
        float4 w1 = *reinterpret_cast<const float4*>(sW + (k + 1) * 64 + c0);
        float4 w2 = *reinterpret_cast<const float4*>(sW + (k + 2) * 64 + c0);
        float4 w3 = *reinterpret_cast<const float4*>(sW + (k + 3) * 64 + c0);
#define FMA4(A, xs, wv) \
        A.x = fmaf(xs, wv.x, A.x); A.y = fmaf(xs, wv.y, A.y); \
        A.z = fmaf(xs, wv.z, A.z); A.w = fmaf(xs, wv.w, A.w);
        FMA4(acc0, x0.x, w0) FMA4(acc0, x0.y, w1) FMA4(acc0, x0.z, w2) FMA4(acc0, x0.w, w3)
        FMA4(acc1, x1.x, w0) FMA4(acc1, x1.y, w1) FMA4(acc1, x1.z, w2) FMA4(acc1, x1.w, w3)
        FMA4(acc2, x2.x, w0) FMA4(acc2, x2.y, w1) FMA4(acc2, x2.z, w2) FMA4(acc2, x2.w, w3)
        FMA4(acc3, x3.x, w0) FMA4(acc3, x3.y, w1) FMA4(acc3, x3.z, w2) FMA4(acc3, x3.w, w3)
#undef FMA4
    }

#define EPI(A, i) { \
        int rg = rowbase + r0 + i; \
        if (rg < nrows) { \
            if (RELU) { \
                A.x = A.x > 0.f ? A.x : 0.01f * A.x; \
                A.y = A.y > 0.f ? A.y : 0.01f * A.y; \
                A.z = A.z > 0.f ? A.z : 0.01f * A.z; \
                A.w = A.w > 0.f ? A.w : 0.01f * A.w; \
            } \
            *reinterpret_cast<float4*>(out + (size_t)rg * 64 + c0) = A; \
        } }
    EPI(acc0, 0) EPI(acc1, 1) EPI(acc2, 2) EPI(acc3, 3)
#undef EPI
}

extern "C" void kernel_launch(void* const* d_in, const int* in_sizes, int n_in,
                              void* d_out, int out_size, void* d_ws, size_t ws_size,
                              hipStream_t stream) {
    const float* feat   = (const float*)d_in[0];
    const int*   esrc   = (const int*)d_in[1];
    const int*   edst   = (const int*)d_in[2];
    const int*   labels = (const int*)d_in[3];
    const float* W_lin  = (const float*)d_in[4];
    const float* b_lin  = (const float*)d_in[5];
    const float* W_lin1 = (const float*)d_in[6];
    const float* b_lin1 = (const float*)d_in[7];
    const float* W_th   = (const float*)d_in[8];
    const float* b_th   = (const float*)d_in[9];

    char* ws = (char*)d_ws;
    unsigned short* g0 = (unsigned short*)(ws + OFF_G0);
    unsigned short* g1 = (unsigned short*)(ws + OFF_G1);
    float* hs   = (float*)(ws + OFF_HS);
    unsigned int* csr = (unsigned int*)(ws + OFF_CSR);
    int* rp     = (int*)(ws + OFF_RP);
    unsigned int* cnt = (unsigned int*)(ws + OFF_CNT);
    float* d2o  = (float*)(ws + OFF_D2O);
    float* d2p  = (float*)(ws + OFF_D2P);
    float* d2n  = (float*)(ws + OFF_D2N);
    float* rdo  = (float*)(ws + OFF_RDO);
    float* rdp  = (float*)(ws + OFF_RDP);
    float* rdn  = (float*)(ws + OFF_RDN);
    float* dvo  = (float*)(ws + OFF_DVO);
    float* dvp  = (float*)(ws + OFF_DVP);
    float* dvn  = (float*)(ws + OFF_DVN);
    int* curp   = (int*)(ws + OFF_CURP);
    int* curn   = (int*)(ws + OFF_CURN);
    int* part   = (int*)(ws + OFF_PART);

    float* out0 = (float*)d_out;
    float* out1 = out0 + (size_t)N_NODES * 64;
    float* out2 = out1 + (size_t)N_NODES * 64;

    const float TH[4][3] = {{0.5f, -0.4f, 0.1f},
                            {0.25f, 0.5f, -0.25f},
                            {0.1f, 0.3f, 0.6f},
                            {0.05f, -0.2f, 0.8f}};

    const int EB = N_EDGES / 256;             // 6250
    const int NB = (N_NODES + 255) / 256;     // 391
    const int SB = (N_NODES + 255) / 256 + 1; // 392 (pad block for scan)
    const int HB = N_NODES / 4;               // 25000 blocks, 1 node/wave64
    const int GB = (N_NODES + 63) / 64;       // 1563 gemm blocks

    // packed degree counters
    hipMemsetAsync(cnt, 0, N_NODES * sizeof(int), stream);
    k_mask_deg<<<EB, 256, 0, stream>>>(esrc, edst, labels, cnt);
    k_dinv<<<NB, 256, 0, stream>>>(cnt, d2o, d2p, d2n, rdo, rdp, rdn, dvo, dvp, dvn);

    // CSR build: scan -> rowptr + cursors; fill splits each row into p|n sections
    k_scan_a<<<SB, 256, 0, stream>>>(cnt, N_NODES, rp, part);
    k_scan_b<<<1, 512, 0, stream>>>(part, SB);
    k_scan_c<<<SB, 256, 0, stream>>>(rp, part, N_NODES, cnt, curp, curn);
    k_fill<<<EB, 256, 0, stream>>>(esrc, edst, labels, curp, curn, csr);

    // ---- o-phase: 8 hops over all edges ----
    k_init_o<<<N_NODES * 32 / 256, 256, 0, stream>>>(feat, dvo, g0, hs);
    unsigned short* ga = g0; unsigned short* gb = g1;
    for (int hop = 0; hop < 8; ++hop) {
        int poly = hop >> 1, k = (hop & 1) + 1;
        int colA = poly * 32;
        float cA = TH[poly][k];
        int colB = -1; float cB = 0.f;
        if (k == 2 && poly < 3) { colB = (poly + 1) * 32; cB = TH[poly + 1][0]; }
        k_hop_o<<<HB, 256, 0, stream>>>(rp, cnt, csr, ga, gb, d2o, rdo, hs, colA, cA, colB, cB);
        unsigned short* t = ga; ga = gb; gb = t;
    }
    k_gemm<128, true><<<GB, 256, 0, stream>>>(hs, W_lin, b_lin, out0, N_NODES);

    // ---- pn-phase: 4 fused hops over split CSR ----
    k_init_pn<<<N_NODES * 32 / 256, 256, 0, stream>>>(feat, dvp, dvn, g0, hs);
    ga = g0; gb = g1;
    for (int hop = 0; hop < 4; ++hop) {
        int poly = hop >> 1, k = (hop & 1) + 1;
        int colAp = poly * 32;       float cAp = TH[poly][k];
        int colAn = 64 + poly * 32;  float cAn = TH[poly + 2][k];
        int colB = -1; float cBp = 0.f, cBn = 0.f;
        if (k == 2 && poly == 0) { colB = 32; cBp = TH[1][0]; cBn = TH[3][0]; }
        k_hop_pn<<<HB, 256, 0, stream>>>(rp, cnt, csr, ga, gb,
                                         d2p, d2n, rdp, rdn, hs,
                                         colAp, cAp, colAn, cAn, colB, cBp, cBn);
        unsigned short* t = ga; ga = gb; gb = t;
    }
    k_gemm<128, true><<<GB, 256, 0, stream>>>(hs, W_lin1, b_lin1, out1, N_NODES);

    // transh
    k_gemm<32, false><<<GB, 256, 0, stream>>>(feat, W_th, b_th, out2, N_NODES);
}

// Round 9
// 803.329 us; speedup vs baseline: 1.1394x; 1.1394x over previous
//
#include <hip/hip_runtime.h>

#define N_NODES 100000
#define N_EDGES 1600000

typedef __attribute__((ext_vector_type(8))) unsigned short ushort8v;

// ---- workspace layout (bytes) ----
// g row: 96 cols bf16 = 192B, order [p(0:32) | o(32:64) | n(64:96)]
#define OFF_G0    0UL            // g ping [N,96] bf16 = 19.2 MB
#define OFF_G1    19200000UL     // g pong
#define OFF_HSO   38400000UL     // hs_o  [N,128] f32 = 51.2 MB
#define OFF_HSPN  89600000UL     // hs_pn [N,128] f32
#define OFF_CSR   140800000UL    // CSR src [E] u32 (per row: p-edges | n-edges)
#define OFF_RP    147200000UL    // rowptr [N] (+scan pad)
#define OFF_CNT   147700000UL    // packed deg<<16 | posdeg, [N] u32
#define OFF_CUR   148200000UL    // u64 packed cursors [N] (curn hi32 | curp lo32)
#define OFF_D2O   149000000UL    // 1/clip(deg) f32 [N]
#define OFF_D2P   149400000UL
#define OFF_D2N   149800000UL
#define OFF_RDO   150200000UL    // sqrt(clip) f32 [N]
#define OFF_RDP   150600000UL
#define OFF_RDN   151000000UL
#define OFF_DVO   151400000UL    // rsqrt(clip) f32 [N]
#define OFF_DVP   151800000UL
#define OFF_DVN   152200000UL
#define OFF_PART  152600000UL    // scan partials [392] int

__device__ __forceinline__ float bf2f(unsigned short h) {
    union { unsigned u; float f; } c; c.u = ((unsigned)h) << 16; return c.f;
}
__device__ __forceinline__ unsigned short f2bf(float x) {
    union { float f; unsigned u; } c; c.f = x;
    unsigned r = (c.u + 0x7FFFu + ((c.u >> 16) & 1u)) >> 16;
    return (unsigned short)r;
}

__global__ __launch_bounds__(256) void k_mask_deg(
    const int* __restrict__ src, const int* __restrict__ dst,
    const int* __restrict__ labels, unsigned int* __restrict__ cnt) {
    int e = blockIdx.x * 256 + threadIdx.x;
    int s = src[e], d = dst[e];
    unsigned int p = (labels[s] == labels[d]) ? 1u : 0u;
    atomicAdd(&cnt[d], 0x10000u + p);   // deg hi16, posdeg lo16
}

__global__ __launch_bounds__(256) void k_dinv(
    const unsigned int* __restrict__ cnt,
    float* __restrict__ d2o, float* __restrict__ d2p, float* __restrict__ d2n,
    float* __restrict__ rdo, float* __restrict__ rdp, float* __restrict__ rdn,
    float* __restrict__ dvo, float* __restrict__ dvp, float* __restrict__ dvn) {
    int v = blockIdx.x * 256 + threadIdx.x;
    if (v >= N_NODES) return;
    unsigned int c = cnt[v];
    int dg = (int)(c >> 16), pg = (int)(c & 0xFFFF), ng = dg - pg;
    float co = (float)max(dg, 1);
    float cp = (float)max(pg, 1);
    float cn = (float)max(ng, 1);
    d2o[v] = 1.f / co; rdo[v] = sqrtf(co); dvo[v] = rsqrtf(co);
    d2p[v] = 1.f / cp; rdp[v] = sqrtf(cp); dvp[v] = rsqrtf(cp);
    d2n[v] = 1.f / cn; rdn[v] = sqrtf(cn); dvn[v] = rsqrtf(cn);
}

// ---- exclusive prefix scan over deg (hi16 of cnt) ----
__global__ __launch_bounds__(256) void k_scan_a(
    const unsigned int* __restrict__ cnt, int n, int* __restrict__ out,
    int* __restrict__ partial) {
    __shared__ int tmp[256];
    int g = blockIdx.x * 256 + threadIdx.x;
    int v = (g < n) ? (int)(cnt[g] >> 16) : 0;
    tmp[threadIdx.x] = v;
    __syncthreads();
    for (int off = 1; off < 256; off <<= 1) {
        int t = (threadIdx.x >= off) ? tmp[threadIdx.x - off] : 0;
        __syncthreads();
        tmp[threadIdx.x] += t;
        __syncthreads();
    }
    out[g] = tmp[threadIdx.x] - v;
    if (threadIdx.x == 255) partial[blockIdx.x] = tmp[255];
}

__global__ __launch_bounds__(512) void k_scan_b(int* __restrict__ partial, int nb) {
    __shared__ int tmp[512];
    int v = (threadIdx.x < nb) ? partial[threadIdx.x] : 0;
    tmp[threadIdx.x] = v;
    __syncthreads();
    for (int off = 1; off < 512; off <<= 1) {
        int t = (threadIdx.x >= off) ? tmp[threadIdx.x - off] : 0;
        __syncthreads();
        tmp[threadIdx.x] += t;
        __syncthreads();
    }
    if (threadIdx.x < nb) partial[threadIdx.x] = tmp[threadIdx.x] - v;
}

// finalize rowptr + init packed u64 cursor (curp = row start, curn = start + pos)
__global__ __launch_bounds__(256) void k_scan_c(
    int* __restrict__ out, const int* __restrict__ partial, int n,
    const unsigned int* __restrict__ cnt, unsigned long long* __restrict__ cur) {
    int g = blockIdx.x * 256 + threadIdx.x;
    int v = out[g] + partial[blockIdx.x];
    out[g] = v;
    if (g < n) {
        unsigned int curp = (unsigned int)v;
        unsigned int curn = (unsigned int)(v + (int)(cnt[g] & 0xFFFF));
        cur[g] = ((unsigned long long)curn << 32) | (unsigned long long)curp;
    }
}

__global__ __launch_bounds__(256) void k_fill(
    const int* __restrict__ src, const int* __restrict__ dst,
    const int* __restrict__ labels, unsigned long long* __restrict__ cur,
    unsigned int* __restrict__ csr) {
    int e = blockIdx.x * 256 + threadIdx.x;
    int s = src[e], d = dst[e];
    if (labels[s] == labels[d]) {
        unsigned long long old = atomicAdd(&cur[d], 1ULL);
        csr[(unsigned int)old] = (unsigned int)s;
    } else {
        unsigned long long old = atomicAdd(&cur[d], 1ULL << 32);
        csr[(unsigned int)(old >> 32)] = (unsigned int)s;
    }
}

// ---- init: g row [p|o|n] = bf16(feat*dv*), hs heads ----
__global__ __launch_bounds__(256) void k_init(
    const float* __restrict__ feat,
    const float* __restrict__ dvo, const float* __restrict__ dvp, const float* __restrict__ dvn,
    unsigned short* __restrict__ g0, float* __restrict__ hs_o, float* __restrict__ hs_pn) {
    int idx = blockIdx.x * 256 + threadIdx.x;   // over N*32
    int v = idx >> 5, c = idx & 31;
    float x = feat[idx];
    g0[v * 96 + c]      = f2bf(x * dvp[v]);
    g0[v * 96 + 32 + c] = f2bf(x * dvo[v]);
    g0[v * 96 + 64 + c] = f2bf(x * dvn[v]);
    hs_o[v * 128 + c]       = 0.5f * x;   // TH[0][0]
    hs_pn[v * 128 + c]      = 0.5f * x;   // p head TH[0][0]
    hs_pn[v * 128 + 64 + c] = 0.1f * x;   // n head TH[2][0]
}

// ---- fused hop (hops 0-3): o + p + n in one pass over the CSR ----
// p-edge gathers 128B window [p|o]; n-edge gathers 128B window [o|n].
__global__ __launch_bounds__(256) void k_hop_fused(
    const int* __restrict__ rp, const unsigned int* __restrict__ cnt,
    const unsigned int* __restrict__ csr,
    const unsigned short* __restrict__ g_old, unsigned short* __restrict__ g_new,
    const float* __restrict__ d2o, const float* __restrict__ d2p, const float* __restrict__ d2n,
    const float* __restrict__ rdo, const float* __restrict__ rdp, const float* __restrict__ rdn,
    float* __restrict__ hs_o, float* __restrict__ hs_pn,
    int colAo, float cAo, int colBo, float cBo,
    int colAp, float cAp, int colBp, float cBp,
    int colAn, float cAn, int colBn, float cBn) {
    int v = (blockIdx.x * 256 + threadIdx.x) >> 6;
    int lane = threadIdx.x & 63;
    int slot = lane >> 3, fl = lane & 7;
    unsigned int c = cnt[v];
    int beg = rp[v];
    int mid = beg + (int)(c & 0xFFFF);
    int end = beg + (int)(c >> 16);
    const ushort8v* gp = reinterpret_cast<const ushort8v*>(g_old);   // 12 units/row
    float a1[8] = {0.f,0.f,0.f,0.f,0.f,0.f,0.f,0.f};  // p-edges: cols 0..63  [p|o]
    float a2[8] = {0.f,0.f,0.f,0.f,0.f,0.f,0.f,0.f};  // n-edges: cols 32..95 [o|n]
    for (int i = beg + slot; i < mid; i += 8) {
        int s = (int)csr[i];
        ushort8v h = gp[s * 12 + fl];
#pragma unroll
        for (int j = 0; j < 8; ++j) a1[j] += bf2f(h[j]);
    }
    for (int i = mid + slot; i < end; i += 8) {
        int s = (int)csr[i];
        ushort8v h = gp[s * 12 + 4 + fl];
#pragma unroll
        for (int j = 0; j < 8; ++j) a2[j] += bf2f(h[j]);
    }
#pragma unroll
    for (int m = 8; m < 64; m <<= 1)
#pragma unroll
        for (int j = 0; j < 8; ++j) {
            a1[j] += __shfl_xor(a1[j], m);
            a2[j] += __shfl_xor(a2[j], m);
        }
    // o-cols: a1 holds o on lanes fl=4..7; a2 holds o on lanes fl=0..3 -> fetch
    float oextra[8];
    int srcl = (lane & 56) | ((fl + 4) & 7);
#pragma unroll
    for (int j = 0; j < 8; ++j) oextra[j] = __shfl(a2[j], srcl);

    if (lane < 4) {                 // p-cols [8fl, 8fl+8)
        float dd = d2p[v], rr = rdp[v];
        ushort8v gh = gp[v * 12 + fl];
        ushort8v go; float fn[8];
#pragma unroll
        for (int j = 0; j < 8; ++j) {
            float gn = bf2f(gh[j]) - a1[j] * dd;
            go[j] = f2bf(gn); fn[j] = gn * rr;
        }
        reinterpret_cast<ushort8v*>(g_new)[v * 12 + fl] = go;
        float* hp = hs_pn + v * 128 + colAp + fl * 8;
#pragma unroll
        for (int j = 0; j < 8; ++j) hp[j] += cAp * fn[j];
        if (colBp >= 0) {
            float* bp = hs_pn + v * 128 + colBp + fl * 8;
#pragma unroll
            for (int j = 0; j < 8; ++j) bp[j] = cBp * fn[j];
        }
    } else if (lane < 8) {          // o-cols [32+8(fl-4), ...)
        float dd = d2o[v], rr = rdo[v];
        ushort8v gh = gp[v * 12 + fl];         // units 4..7 = o cols
        ushort8v go; float fn[8];
#pragma unroll
        for (int j = 0; j < 8; ++j) {
            float gn = bf2f(gh[j]) - (a1[j] + oextra[j]) * dd;
            go[j] = f2bf(gn); fn[j] = gn * rr;
        }
        reinterpret_cast<ushort8v*>(g_new)[v * 12 + fl] = go;
        float* hp = hs_o + v * 128 + colAo + (fl - 4) * 8;
#pragma unroll
        for (int j = 0; j < 8; ++j) hp[j] += cAo * fn[j];
        if (colBo >= 0) {
            float* bp = hs_o + v * 128 + colBo + (fl - 4) * 8;
#pragma unroll
            for (int j = 0; j < 8; ++j) bp[j] = cBo * fn[j];
        }
    } else if (lane >= 12 && lane < 16) {   // slot1 fl=4..7: n-cols [64+8(fl-4),...)
        float dd = d2n[v], rr = rdn[v];
        ushort8v gh = gp[v * 12 + fl + 4];     // units 8..11 = n cols
        ushort8v go; float fn[8];
#pragma unroll
        for (int j = 0; j < 8; ++j) {
            float gn = bf2f(gh[j]) - a2[j] * dd;
            go[j] = f2bf(gn); fn[j] = gn * rr;
        }
        reinterpret_cast<ushort8v*>(g_new)[v * 12 + fl + 4] = go;
        float* hp = hs_pn + v * 128 + colAn + (fl - 4) * 8;
#pragma unroll
        for (int j = 0; j < 8; ++j) hp[j] += cAn * fn[j];
        if (colBn >= 0) {
            float* bp = hs_pn + v * 128 + colBn + (fl - 4) * 8;
#pragma unroll
            for (int j = 0; j < 8; ++j) bp[j] = cBn * fn[j];
        }
    }
}

// ---- solo o-hop (hops 4-7): o slice of the 96-col rows (R7-proven shape) ----
__global__ __launch_bounds__(256) void k_hop_o(
    const int* __restrict__ rp, const unsigned int* __restrict__ cnt,
    const unsigned int* __restrict__ csr,
    const unsigned short* __restrict__ g_old, unsigned short* __restrict__ g_new,
    const float* __restrict__ d2, const float* __restrict__ rd,
    float* __restrict__ hs, int colA, float cA, int colB, float cB) {
    int v = (blockIdx.x * 256 + threadIdx.x) >> 6;
    int lane = threadIdx.x & 63;
    int slot = lane >> 3, fl = lane & 7;
    int beg = rp[v];
    int end = beg + (int)(cnt[v] >> 16);
    const ushort4* gp = reinterpret_cast<const ushort4*>(g_old);  // 24 units/row, o at 8..15
    float4 acc = make_float4(0.f, 0.f, 0.f, 0.f);
    for (int i = beg + slot; i < end; i += 8) {
        int s = (int)csr[i];
        ushort4 h = gp[s * 24 + 8 + fl];
        acc.x += bf2f(h.x); acc.y += bf2f(h.y);
        acc.z += bf2f(h.z); acc.w += bf2f(h.w);
    }
#pragma unroll
    for (int m = 8; m < 64; m <<= 1) {
        acc.x += __shfl_xor(acc.x, m);
        acc.y += __shfl_xor(acc.y, m);
        acc.z += __shfl_xor(acc.z, m);
        acc.w += __shfl_xor(acc.w, m);
    }
    if (slot == 0) {
        float dd = d2[v], rr = rd[v];
        ushort4 gh = gp[v * 24 + 8 + fl];
        float4 gn;
        gn.x = bf2f(gh.x) - acc.x * dd; gn.y = bf2f(gh.y) - acc.y * dd;
        gn.z = bf2f(gh.z) - acc.z * dd; gn.w = bf2f(gh.w) - acc.w * dd;
        ushort4 go;
        go.x = f2bf(gn.x); go.y = f2bf(gn.y); go.z = f2bf(gn.z); go.w = f2bf(gn.w);
        reinterpret_cast<ushort4*>(g_new)[v * 24 + 8 + fl] = go;
        float4 fn;
        fn.x = gn.x * rr; fn.y = gn.y * rr; fn.z = gn.z * rr; fn.w = gn.w * rr;
        float4* hp = reinterpret_cast<float4*>(hs + v * 128 + colA) + fl;
        float4 h = *hp;
        h.x += cA * fn.x; h.y += cA * fn.y; h.z += cA * fn.z; h.w += cA * fn.w;
        *hp = h;
        if (colB >= 0) {
            reinterpret_cast<float4*>(hs + v * 128 + colB)[fl] =
                make_float4(cB * fn.x, cB * fn.y, cB * fn.z, cB * fn.w);
        }
    }
}

// ---- GEMM: out[N,64] = act(X[N,KDIM] @ W[KDIM,64] + b) ----
template <int KDIM, bool RELU>
__global__ __launch_bounds__(256) void k_gemm(
    const float* __restrict__ X, const float* __restrict__ W,
    const float* __restrict__ bias, float* __restrict__ out, int nrows) {
    constexpr int SXP = KDIM + 4;
    __shared__ float sW[KDIM * 64];
    __shared__ float sX[64 * SXP];
    int tid = threadIdx.x;
    int rowbase = blockIdx.x * 64;

    for (int i = tid; i < KDIM * 16; i += 256)
        reinterpret_cast<float4*>(sW)[i] = reinterpret_cast<const float4*>(W)[i];

    constexpr int QF4 = KDIM / 4;
    constexpr int RPP = 256 / QF4;
    int q = tid & (QF4 - 1);
    int rloc = tid / QF4;
#pragma unroll
    for (int pass = 0; pass < 64 / RPP; ++pass) {
        int r = rloc + pass * RPP;
        int rg = rowbase + r;
        float4 v = make_float4(0.f, 0.f, 0.f, 0.f);
        if (rg < nrows) v = reinterpret_cast<const float4*>(X + (size_t)rg * KDIM)[q];
        float* dst = sX + r * SXP + q * 4;
        dst[0] = v.x; dst[1] = v.y; dst[2] = v.z; dst[3] = v.w;
    }
    __syncthreads();

    int c0 = (tid & 15) * 4;
    int r0 = (tid >> 4) * 4;
    float4 bv = reinterpret_cast<const float4*>(bias)[tid & 15];
    float4 acc0 = bv, acc1 = bv, acc2 = bv, acc3 = bv;

#pragma unroll 4
    for (int k4 = 0; k4 < KDIM / 4; ++k4) {
        int k = k4 * 4;
        float4 x0 = *reinterpret_cast<const float4*>(sX + (r0 + 0) * SXP + k);
        float4 x1 = *reinterpret_cast<const float4*>(sX + (r0 + 1) * SXP + k);
        float4 x2 = *reinterpret_cast<const float4*>(sX + (r0 + 2) * SXP + k);
        float4 x3 = *reinterpret_cast<const float4*>(sX + (r0 + 3) * SXP + k);
        float4 w0 = *reinterpret_cast<const float4*>(sW + (k + 0) * 64 + c0);
        float4 w1 = *reinterpret_cast<const float4*>(sW + (k + 1) * 64 + c0);
        float4 w2 = *reinterpret_cast<const float4*>(sW + (k + 2) * 64 + c0);
        float4 w3 = *reinterpret_cast<const float4*>(sW + (k + 3) * 64 + c0);
#define FMA4(A, xs, wv) \
        A.x = fmaf(xs, wv.x, A.x); A.y = fmaf(xs, wv.y, A.y); \
        A.z = fmaf(xs, wv.z, A.z); A.w = fmaf(xs, wv.w, A.w);
        FMA4(acc0, x0.x, w0) FMA4(acc0, x0.y, w1) FMA4(acc0, x0.z, w2) FMA4(acc0, x0.w, w3)
        FMA4(acc1, x1.x, w0) FMA4(acc1, x1.y, w1) FMA4(acc1, x1.z, w2) FMA4(acc1, x1.w, w3)
        FMA4(acc2, x2.x, w0) FMA4(acc2, x2.y, w1) FMA4(acc2, x2.z, w2) FMA4(acc2, x2.w, w3)
        FMA4(acc3, x3.x, w0) FMA4(acc3, x3.y, w1) FMA4(acc3, x3.z, w2) FMA4(acc3, x3.w, w3)
#undef FMA4
    }

#define EPI(A, i) { \
        int rg = rowbase + r0 + i; \
        if (rg < nrows) { \
            if (RELU) { \
                A.x = A.x > 0.f ? A.x : 0.01f * A.x; \
                A.y = A.y > 0.f ? A.y : 0.01f * A.y; \
                A.z = A.z > 0.f ? A.z : 0.01f * A.z; \
                A.w = A.w > 0.f ? A.w : 0.01f * A.w; \
            } \
            *reinterpret_cast<float4*>(out + (size_t)rg * 64 + c0) = A; \
        } }
    EPI(acc0, 0) EPI(acc1, 1) EPI(acc2, 2) EPI(acc3, 3)
#undef EPI
}

extern "C" void kernel_launch(void* const* d_in, const int* in_sizes, int n_in,
                              void* d_out, int out_size, void* d_ws, size_t ws_size,
                              hipStream_t stream) {
    const float* feat   = (const float*)d_in[0];
    const int*   esrc   = (const int*)d_in[1];
    const int*   edst   = (const int*)d_in[2];
    const int*   labels = (const int*)d_in[3];
    const float* W_lin  = (const float*)d_in[4];
    const float* b_lin  = (const float*)d_in[5];
    const float* W_lin1 = (const float*)d_in[6];
    const float* b_lin1 = (const float*)d_in[7];
    const float* W_th   = (const float*)d_in[8];
    const float* b_th   = (const float*)d_in[9];

    char* ws = (char*)d_ws;
    unsigned short* g0 = (unsigned short*)(ws + OFF_G0);
    unsigned short* g1 = (unsigned short*)(ws + OFF_G1);
    float* hs_o  = (float*)(ws + OFF_HSO);
    float* hs_pn = (float*)(ws + OFF_HSPN);
    unsigned int* csr = (unsigned int*)(ws + OFF_CSR);
    int* rp     = (int*)(ws + OFF_RP);
    unsigned int* cnt = (unsigned int*)(ws + OFF_CNT);
    unsigned long long* cur = (unsigned long long*)(ws + OFF_CUR);
    float* d2o  = (float*)(ws + OFF_D2O);
    float* d2p  = (float*)(ws + OFF_D2P);
    float* d2n  = (float*)(ws + OFF_D2N);
    float* rdo  = (float*)(ws + OFF_RDO);
    float* rdp  = (float*)(ws + OFF_RDP);
    float* rdn  = (float*)(ws + OFF_RDN);
    float* dvo  = (float*)(ws + OFF_DVO);
    float* dvp  = (float*)(ws + OFF_DVP);
    float* dvn  = (float*)(ws + OFF_DVN);
    int* part   = (int*)(ws + OFF_PART);

    float* out0 = (float*)d_out;
    float* out1 = out0 + (size_t)N_NODES * 64;
    float* out2 = out1 + (size_t)N_NODES * 64;

    const float TH[4][3] = {{0.5f, -0.4f, 0.1f},
                            {0.25f, 0.5f, -0.25f},
                            {0.1f, 0.3f, 0.6f},
                            {0.05f, -0.2f, 0.8f}};

    const int EB = N_EDGES / 256;             // 6250
    const int NB = (N_NODES + 255) / 256;     // 391
    const int SB = (N_NODES + 255) / 256 + 1; // 392 (pad block for scan)
    const int HB = N_NODES / 4;               // 25000 blocks, 1 node/wave64
    const int GB = (N_NODES + 63) / 64;       // 1563 gemm blocks

    hipMemsetAsync(cnt, 0, N_NODES * sizeof(int), stream);
    k_mask_deg<<<EB, 256, 0, stream>>>(esrc, edst, labels, cnt);
    k_dinv<<<NB, 256, 0, stream>>>(cnt, d2o, d2p, d2n, rdo, rdp, rdn, dvo, dvp, dvn);

    k_scan_a<<<SB, 256, 0, stream>>>(cnt, N_NODES, rp, part);
    k_scan_b<<<1, 512, 0, stream>>>(part, SB);
    k_scan_c<<<SB, 256, 0, stream>>>(rp, part, N_NODES, cnt, cur);
    k_fill<<<EB, 256, 0, stream>>>(esrc, edst, labels, cur, csr);

    k_init<<<N_NODES * 32 / 256, 256, 0, stream>>>(feat, dvo, dvp, dvn, g0, hs_o, hs_pn);

    // ---- fused hops 0-3: o + p + n per pass ----
    unsigned short* ga = g0; unsigned short* gb = g1;
    for (int hop = 0; hop < 4; ++hop) {
        int poly = hop >> 1, kk = (hop & 1) + 1;
        int colAo = poly * 32;       float cAo = TH[poly][kk];
        int colAp = poly * 32;       float cAp = TH[poly][kk];
        int colAn = 64 + poly * 32;  float cAn = TH[poly + 2][kk];
        int colBo = -1, colBp = -1, colBn = -1;
        float cBo = 0.f, cBp = 0.f, cBn = 0.f;
        if (kk == 2) {
            colBo = (poly + 1) * 32; cBo = TH[poly + 1][0];
            if (poly == 0) { colBp = 32; cBp = TH[1][0]; colBn = 96; cBn = TH[3][0]; }
        }
        k_hop_fused<<<HB, 256, 0, stream>>>(rp, cnt, csr, ga, gb,
                                            d2o, d2p, d2n, rdo, rdp, rdn, hs_o, hs_pn,
                                            colAo, cAo, colBo, cBo,
                                            colAp, cAp, colBp, cBp,
                                            colAn, cAn, colBn, cBn);
        unsigned short* t = ga; ga = gb; gb = t;
    }
    k_gemm<128, true><<<GB, 256, 0, stream>>>(hs_pn, W_lin1, b_lin1, out1, N_NODES);

    // ---- solo o-hops 4-7 ----
    for (int hop = 4; hop < 8; ++hop) {
        int poly = hop >> 1, kk = (hop & 1) + 1;
        int colA = poly * 32;
        float cA = TH[poly][kk];
        int colB = -1; float cB = 0.f;
        if (kk == 2 && poly < 3) { colB = (poly + 1) * 32; cB = TH[poly + 1][0]; }
        k_hop_o<<<HB, 256, 0, stream>>>(rp, cnt, csr, ga, gb, d2o, rdo, hs_o, colA, cA, colB, cB);
        unsigned short* t = ga; ga = gb; gb = t;
    }
    k_gemm<128, true><<<GB, 256, 0, stream>>>(hs_o, W_lin, b_lin, out0, N_NODES);

    // transh
    k_gemm<32, false><<<GB, 256, 0, stream>>>(feat, W_th, b_th, out2, N_NODES);
}

// Round 10
// 778.369 us; speedup vs baseline: 1.1760x; 1.0321x over previous
//
#include <hip/hip_runtime.h>

#define N_NODES 100000
#define N_EDGES 1600000

typedef __attribute__((ext_vector_type(8))) unsigned short ushort8v;

// ---- workspace layout (bytes) ----
// F_k: fused-phase state [N,96] bf16, row = [p(0:32)|o(32:64)|n(64:96)], k=0..4
// O_k: solo-phase o state [N,32] bf16, k=5..8
#define OFF_F0    0UL
#define OFF_F1    19200000UL
#define OFF_F2    38400000UL
#define OFF_F3    57600000UL
#define OFF_F4    76800000UL
#define OFF_O5    96000000UL
#define OFF_O6    102400000UL
#define OFF_O7    108800000UL
#define OFF_O8    115200000UL
#define OFF_CSR   121600000UL    // CSR src [E] u32 (per row: p-edges | n-edges)
#define OFF_RP    128000000UL    // rowptr [N] (+scan pad)
#define OFF_CNT   128500000UL    // packed deg<<16 | posdeg [N] u32
#define OFF_CUR   129000000UL    // u64 packed cursors [N]
#define OFF_D2O   129800000UL
#define OFF_D2P   130200000UL
#define OFF_D2N   130600000UL
#define OFF_RDO   131000000UL
#define OFF_RDP   131400000UL
#define OFF_RDN   131800000UL
#define OFF_DVO   132200000UL
#define OFF_DVP   132600000UL
#define OFF_DVN   133000000UL
#define OFF_WCO   133400000UL    // folded weights o: [9][32][64] f32
#define OFF_WCPN  133480000UL    // folded weights pn: [10][32][64] f32 (p0..4,n0..4)
#define OFF_PART  133570000UL    // scan partials

__device__ __forceinline__ float bf2f(unsigned short h) {
    union { unsigned u; float f; } c; c.u = ((unsigned)h) << 16; return c.f;
}
__device__ __forceinline__ unsigned short f2bf(float x) {
    union { float f; unsigned u; } c; c.f = x;
    unsigned r = (c.u + 0x7FFFu + ((c.u >> 16) & 1u)) >> 16;
    return (unsigned short)r;
}

__device__ __constant__ float c_TH[4][3] = {
    {0.5f, -0.4f, 0.1f}, {0.25f, 0.5f, -0.25f},
    {0.1f, 0.3f, 0.6f}, {0.05f, -0.2f, 0.8f}};

__global__ __launch_bounds__(256) void k_mask_deg(
    const int* __restrict__ src, const int* __restrict__ dst,
    const int* __restrict__ labels, unsigned int* __restrict__ cnt) {
    int e = blockIdx.x * 256 + threadIdx.x;
    int s = src[e], d = dst[e];
    unsigned int p = (labels[s] == labels[d]) ? 1u : 0u;
    atomicAdd(&cnt[d], 0x10000u + p);
}

__global__ __launch_bounds__(256) void k_dinv(
    const unsigned int* __restrict__ cnt,
    float* __restrict__ d2o, float* __restrict__ d2p, float* __restrict__ d2n,
    float* __restrict__ rdo, float* __restrict__ rdp, float* __restrict__ rdn,
    float* __restrict__ dvo, float* __restrict__ dvp, float* __restrict__ dvn) {
    int v = blockIdx.x * 256 + threadIdx.x;
    if (v >= N_NODES) return;
    unsigned int c = cnt[v];
    int dg = (int)(c >> 16), pg = (int)(c & 0xFFFF), ng = dg - pg;
    float co = (float)max(dg, 1);
    float cp = (float)max(pg, 1);
    float cn = (float)max(ng, 1);
    d2o[v] = 1.f / co; rdo[v] = sqrtf(co); dvo[v] = rsqrtf(co);
    d2p[v] = 1.f / cp; rdp[v] = sqrtf(cp); dvp[v] = rsqrtf(cp);
    d2n[v] = 1.f / cn; rdn[v] = sqrtf(cn); dvn[v] = rsqrtf(cn);
}

// ---- folded-weight precompute ----
__global__ __launch_bounds__(256) void k_wc_o(const float* __restrict__ W, float* __restrict__ Wc) {
    int idx = blockIdx.x * 256 + threadIdx.x;
    if (idx >= 9 * 2048) return;
    int k = idx >> 11, rem = idx & 2047, r = rem >> 6, c = rem & 63;
    float v = 0.f;
#pragma unroll
    for (int j = 0; j < 4; ++j) {
        int m = k - 2 * j;
        if (m >= 0 && m <= 2) v += c_TH[j][m] * W[(32 * j + r) * 64 + c];
    }
    Wc[idx] = v;
}

__global__ __launch_bounds__(256) void k_wc_pn(const float* __restrict__ W1, float* __restrict__ Wc) {
    int idx = blockIdx.x * 256 + threadIdx.x;
    if (idx >= 10 * 2048) return;
    int k5 = idx >> 11, rem = idx & 2047, r = rem >> 6, c = rem & 63;
    float v = 0.f;
    if (k5 < 5) {         // p: polys 0,1 -> W1 rows [0:64)
#pragma unroll
        for (int j = 0; j < 2; ++j) {
            int m = k5 - 2 * j;
            if (m >= 0 && m <= 2) v += c_TH[j][m] * W1[(32 * j + r) * 64 + c];
        }
    } else {              // n: polys 2,3 -> W1 rows [64:128)
        int k = k5 - 5;
#pragma unroll
        for (int j = 0; j < 2; ++j) {
            int m = k - 2 * j;
            if (m >= 0 && m <= 2) v += c_TH[2 + j][m] * W1[(32 * (j + 2) + r) * 64 + c];
        }
    }
    Wc[idx] = v;
}

// ---- exclusive prefix scan over deg (hi16 of cnt) ----
__global__ __launch_bounds__(256) void k_scan_a(
    const unsigned int* __restrict__ cnt, int n, int* __restrict__ out,
    int* __restrict__ partial) {
    __shared__ int tmp[256];
    int g = blockIdx.x * 256 + threadIdx.x;
    int v = (g < n) ? (int)(cnt[g] >> 16) : 0;
    tmp[threadIdx.x] = v;
    __syncthreads();
    for (int off = 1; off < 256; off <<= 1) {
        int t = (threadIdx.x >= off) ? tmp[threadIdx.x - off] : 0;
        __syncthreads();
        tmp[threadIdx.x] += t;
        __syncthreads();
    }
    out[g] = tmp[threadIdx.x] - v;
    if (threadIdx.x == 255) partial[blockIdx.x] = tmp[255];
}

__global__ __launch_bounds__(512) void k_scan_b(int* __restrict__ partial, int nb) {
    __shared__ int tmp[512];
    int v = (threadIdx.x < nb) ? partial[threadIdx.x] : 0;
    tmp[threadIdx.x] = v;
    __syncthreads();
    for (int off = 1; off < 512; off <<= 1) {
        int t = (threadIdx.x >= off) ? tmp[threadIdx.x - off] : 0;
        __syncthreads();
        tmp[threadIdx.x] += t;
        __syncthreads();
    }
    if (threadIdx.x < nb) partial[threadIdx.x] = tmp[threadIdx.x] - v;
}

__global__ __launch_bounds__(256) void k_scan_c(
    int* __restrict__ out, const int* __restrict__ partial, int n,
    const unsigned int* __restrict__ cnt, unsigned long long* __restrict__ cur) {
    int g = blockIdx.x * 256 + threadIdx.x;
    int v = out[g] + partial[blockIdx.x];
    out[g] = v;
    if (g < n) {
        unsigned int curp = (unsigned int)v;
        unsigned int curn = (unsigned int)(v + (int)(cnt[g] & 0xFFFF));
        cur[g] = ((unsigned long long)curn << 32) | (unsigned long long)curp;
    }
}

__global__ __launch_bounds__(256) void k_fill(
    const int* __restrict__ src, const int* __restrict__ dst,
    const int* __restrict__ labels, unsigned long long* __restrict__ cur,
    unsigned int* __restrict__ csr) {
    int e = blockIdx.x * 256 + threadIdx.x;
    int s = src[e], d = dst[e];
    if (labels[s] == labels[d]) {
        unsigned long long old = atomicAdd(&cur[d], 1ULL);
        csr[(unsigned int)old] = (unsigned int)s;
    } else {
        unsigned long long old = atomicAdd(&cur[d], 1ULL << 32);
        csr[(unsigned int)(old >> 32)] = (unsigned int)s;
    }
}

// ---- init: F0 row [p|o|n] = bf16(feat * dv*) ----
__global__ __launch_bounds__(256) void k_init(
    const float* __restrict__ feat,
    const float* __restrict__ dvo, const float* __restrict__ dvp, const float* __restrict__ dvn,
    unsigned short* __restrict__ g0) {
    int idx = blockIdx.x * 256 + threadIdx.x;   // over N*32
    int v = idx >> 5, c = idx & 31;
    float x = feat[idx];
    g0[v * 96 + c]      = f2bf(x * dvp[v]);
    g0[v * 96 + 32 + c] = f2bf(x * dvo[v]);
    g0[v * 96 + 64 + c] = f2bf(x * dvn[v]);
}

// ---- fused hop: o + p + n in one CSR pass; no hs ----
__global__ __launch_bounds__(256) void k_hop_fused(
    const int* __restrict__ rp, const unsigned int* __restrict__ cnt,
    const unsigned int* __restrict__ csr,
    const unsigned short* __restrict__ g_old, unsigned short* __restrict__ g_new,
    const float* __restrict__ d2o, const float* __restrict__ d2p, const float* __restrict__ d2n) {
    int v = (blockIdx.x * 256 + threadIdx.x) >> 6;
    int lane = threadIdx.x & 63;
    int slot = lane >> 3, fl = lane & 7;
    unsigned int c = cnt[v];
    int beg = rp[v];
    int mid = beg + (int)(c & 0xFFFF);
    int end = beg + (int)(c >> 16);
    const ushort8v* gp = reinterpret_cast<const ushort8v*>(g_old);   // 12 units/row
    float a1[8] = {0.f,0.f,0.f,0.f,0.f,0.f,0.f,0.f};  // p-edges window [p|o]
    float a2[8] = {0.f,0.f,0.f,0.f,0.f,0.f,0.f,0.f};  // n-edges window [o|n]
    for (int i = beg + slot; i < mid; i += 8) {
        int s = (int)csr[i];
        ushort8v h = gp[s * 12 + fl];
#pragma unroll
        for (int j = 0; j < 8; ++j) a1[j] += bf2f(h[j]);
    }
    for (int i = mid + slot; i < end; i += 8) {
        int s = (int)csr[i];
        ushort8v h = gp[s * 12 + 4 + fl];
#pragma unroll
        for (int j = 0; j < 8; ++j) a2[j] += bf2f(h[j]);
    }
#pragma unroll
    for (int m = 8; m < 64; m <<= 1)
#pragma unroll
        for (int j = 0; j < 8; ++j) {
            a1[j] += __shfl_xor(a1[j], m);
            a2[j] += __shfl_xor(a2[j], m);
        }
    float oextra[8];
    int srcl = (lane & 56) | ((fl + 4) & 7);
#pragma unroll
    for (int j = 0; j < 8; ++j) oextra[j] = __shfl(a2[j], srcl);

    if (lane < 4) {                 // p units 0..3
        float dd = d2p[v];
        ushort8v gh = gp[v * 12 + fl];
        ushort8v go;
#pragma unroll
        for (int j = 0; j < 8; ++j) go[j] = f2bf(bf2f(gh[j]) - a1[j] * dd);
        reinterpret_cast<ushort8v*>(g_new)[v * 12 + fl] = go;
    } else if (lane < 8) {          // o units 4..7
        float dd = d2o[v];
        ushort8v gh = gp[v * 12 + fl];
        ushort8v go;
#pragma unroll
        for (int j = 0; j < 8; ++j) go[j] = f2bf(bf2f(gh[j]) - (a1[j] + oextra[j]) * dd);
        reinterpret_cast<ushort8v*>(g_new)[v * 12 + fl] = go;
    } else if (lane >= 12 && lane < 16) {   // n units 8..11
        float dd = d2n[v];
        ushort8v gh = gp[v * 12 + fl + 4];
        ushort8v go;
#pragma unroll
        for (int j = 0; j < 8; ++j) go[j] = f2bf(bf2f(gh[j]) - a2[j] * dd);
        reinterpret_cast<ushort8v*>(g_new)[v * 12 + fl + 4] = go;
    }
}

// ---- solo o-hop: gather 32-col slice (stride/base parameterized), write compact ----
__global__ __launch_bounds__(256) void k_hop_o(
    const int* __restrict__ rp, const unsigned int* __restrict__ cnt,
    const unsigned int* __restrict__ csr,
    const unsigned short* __restrict__ g_old, int stride_u4,
    unsigned short* __restrict__ g_new, const float* __restrict__ d2) {
    int v = (blockIdx.x * 256 + threadIdx.x) >> 6;
    int lane = threadIdx.x & 63;
    int slot = lane >> 3, fl = lane & 7;
    int beg = rp[v];
    int end = beg + (int)(cnt[v] >> 16);
    const ushort4* gp = reinterpret_cast<const ushort4*>(g_old);
    float4 acc = make_float4(0.f, 0.f, 0.f, 0.f);
    for (int i = beg + slot; i < end; i += 8) {
        int s = (int)csr[i];
        ushort4 h = gp[s * stride_u4 + fl];
        acc.x += bf2f(h.x); acc.y += bf2f(h.y);
        acc.z += bf2f(h.z); acc.w += bf2f(h.w);
    }
#pragma unroll
    for (int m = 8; m < 64; m <<= 1) {
        acc.x += __shfl_xor(acc.x, m);
        acc.y += __shfl_xor(acc.y, m);
        acc.z += __shfl_xor(acc.z, m);
        acc.w += __shfl_xor(acc.w, m);
    }
    if (slot == 0) {
        float dd = d2[v];
        ushort4 gh = gp[v * stride_u4 + fl];
        ushort4 go;
        go.x = f2bf(bf2f(gh.x) - acc.x * dd);
        go.y = f2bf(bf2f(gh.y) - acc.y * dd);
        go.z = f2bf(bf2f(gh.z) - acc.z * dd);
        go.w = f2bf(bf2f(gh.w) - acc.w * dd);
        reinterpret_cast<ushort4*>(g_new)[v * 8 + fl] = go;
    }
}

// ---- folded GEMM: out = leaky(Σ_k (slice_k ⊙ scale) @ Wc_k + b) ----
struct SliceArgs { const unsigned short* ptr[10]; int stride[10]; };

template <int NS>
__global__ __launch_bounds__(256) void k_gemm_fold(
    SliceArgs sl, const float* __restrict__ scA, const float* __restrict__ scB, int nA,
    const float* __restrict__ Wc, const float* __restrict__ bias,
    float* __restrict__ out, int nrows) {
    __shared__ float sX[2][64 * 36];
    __shared__ float sW[2][2048];
    int tid = threadIdx.x;
    int rowbase = blockIdx.x * 64;
    int u = tid & 3, rr = tid >> 2;          // staging coords: 64 rows x 4 chunks
    int rgs = rowbase + rr;

#define STAGE(k, b) { \
        float sc = 0.f; ushort8v h = (ushort8v)0; \
        if (rgs < nrows) { \
            sc = ((k) < nA) ? scA[rgs] : scB[rgs]; \
            h = reinterpret_cast<const ushort8v*>(sl.ptr[k] + (size_t)rgs * sl.stride[k])[u]; \
        } \
        float* dx = &sX[b][rr * 36 + u * 8]; \
        _Pragma("unroll") \
        for (int j = 0; j < 8; ++j) dx[j] = bf2f(h[j]) * sc; \
        const float4* wsrc = reinterpret_cast<const float4*>(Wc + (k) * 2048); \
        float4* wdst = reinterpret_cast<float4*>(sW[b]); \
        for (int i = tid; i < 512; i += 256) wdst[i] = wsrc[i]; \
    }

    int c0 = (tid & 15) * 4;
    int r0 = (tid >> 4) * 4;
    float4 acc0 = reinterpret_cast<const float4*>(bias)[tid & 15];
    float4 acc1 = acc0, acc2 = acc0, acc3 = acc0;

    STAGE(0, 0);
    int buf = 0;
    for (int k = 0; k < NS; ++k) {
        __syncthreads();
        if (k + 1 < NS) STAGE(k + 1, buf ^ 1);
        const float* xb = sX[buf];
        const float* wb = sW[buf];
#pragma unroll
        for (int k4 = 0; k4 < 8; ++k4) {
            int kk = k4 * 4;
            float4 x0 = *reinterpret_cast<const float4*>(xb + (r0 + 0) * 36 + kk);
            float4 x1 = *reinterpret_cast<const float4*>(xb + (r0 + 1) * 36 + kk);
            float4 x2 = *reinterpret_cast<const float4*>(xb + (r0 + 2) * 36 + kk);
            float4 x3 = *reinterpret_cast<const float4*>(xb + (r0 + 3) * 36 + kk);
            float4 w0 = *reinterpret_cast<const float4*>(wb + (kk + 0) * 64 + c0);
            float4 w1 = *reinterpret_cast<const float4*>(wb + (kk + 1) * 64 + c0);
            float4 w2 = *reinterpret_cast<const float4*>(wb + (kk + 2) * 64 + c0);
            float4 w3 = *reinterpret_cast<const float4*>(wb + (kk + 3) * 64 + c0);
#define FMA4(A, xs, wv) \
            A.x = fmaf(xs, wv.x, A.x); A.y = fmaf(xs, wv.y, A.y); \
            A.z = fmaf(xs, wv.z, A.z); A.w = fmaf(xs, wv.w, A.w);
            FMA4(acc0, x0.x, w0) FMA4(acc0, x0.y, w1) FMA4(acc0, x0.z, w2) FMA4(acc0, x0.w, w3)
            FMA4(acc1, x1.x, w0) FMA4(acc1, x1.y, w1) FMA4(acc1, x1.z, w2) FMA4(acc1, x1.w, w3)
            FMA4(acc2, x2.x, w0) FMA4(acc2, x2.y, w1) FMA4(acc2, x2.z, w2) FMA4(acc2, x2.w, w3)
            FMA4(acc3, x3.x, w0) FMA4(acc3, x3.y, w1) FMA4(acc3, x3.z, w2) FMA4(acc3, x3.w, w3)
#undef FMA4
        }
        buf ^= 1;
    }
#undef STAGE

#define EPI(A, i) { \
        int rg = rowbase + r0 + i; \
        if (rg < nrows) { \
            A.x = A.x > 0.f ? A.x : 0.01f * A.x; \
            A.y = A.y > 0.f ? A.y : 0.01f * A.y; \
            A.z = A.z > 0.f ? A.z : 0.01f * A.z; \
            A.w = A.w > 0.f ? A.w : 0.01f * A.w; \
            *reinterpret_cast<float4*>(out + (size_t)rg * 64 + c0) = A; \
        } }
    EPI(acc0, 0) EPI(acc1, 1) EPI(acc2, 2) EPI(acc3, 3)
#undef EPI
}

// ---- plain GEMM for transh (K=32, f32 X) ----
template <int KDIM, bool RELU>
__global__ __launch_bounds__(256) void k_gemm(
    const float* __restrict__ X, const float* __restrict__ W,
    const float* __restrict__ bias, float* __restrict__ out, int nrows) {
    constexpr int SXP = KDIM + 4;
    __shared__ float sW[KDIM * 64];
    __shared__ float sX[64 * SXP];
    int tid = threadIdx.x;
    int rowbase = blockIdx.x * 64;
    for (int i = tid; i < KDIM * 16; i += 256)
        reinterpret_cast<float4*>(sW)[i] = reinterpret_cast<const float4*>(W)[i];
    constexpr int QF4 = KDIM / 4;
    constexpr int RPP = 256 / QF4;
    int q = tid & (QF4 - 1);
    int rloc = tid / QF4;
#pragma unroll
    for (int pass = 0; pass < 64 / RPP; ++pass) {
        int r = rloc + pass * RPP;
        int rg = rowbase + r;
        float4 v = make_float4(0.f, 0.f, 0.f, 0.f);
        if (rg < nrows) v = reinterpret_cast<const float4*>(X + (size_t)rg * KDIM)[q];
        float* dst = sX + r * SXP + q * 4;
        dst[0] = v.x; dst[1] = v.y; dst[2] = v.z; dst[3] = v.w;
    }
    __syncthreads();
    int c0 = (tid & 15) * 4;
    int r0 = (tid >> 4) * 4;
    float4 bv = reinterpret_cast<const float4*>(bias)[tid & 15];
    float4 acc0 = bv, acc1 = bv, acc2 = bv, acc3 = bv;
#pragma unroll 4
    for (int k4 = 0; k4 < KDIM / 4; ++k4) {
        int k = k4 * 4;
        float4 x0 = *reinterpret_cast<const float4*>(sX + (r0 + 0) * SXP + k);
        float4 x1 = *reinterpret_cast<const float4*>(sX + (r0 + 1) * SXP + k);
        float4 x2 = *reinterpret_cast<const float4*>(sX + (r0 + 2) * SXP + k);
        float4 x3 = *reinterpret_cast<const float4*>(sX + (r0 + 3) * SXP + k);
        float4 w0 = *reinterpret_cast<const float4*>(sW + (k + 0) * 64 + c0);
        float4 w1 = *reinterpret_cast<const float4*>(sW + (k + 1) * 64 + c0);
        float4 w2 = *reinterpret_cast<const float4*>(sW + (k + 2) * 64 + c0);
        float4 w3 = *reinterpret_cast<const float4*>(sW + (k + 3) * 64 + c0);
#define FMA4(A, xs, wv) \
        A.x = fmaf(xs, wv.x, A.x); A.y = fmaf(xs, wv.y, A.y); \
        A.z = fmaf(xs, wv.z, A.z); A.w = fmaf(xs, wv.w, A.w);
        FMA4(acc0, x0.x, w0) FMA4(acc0, x0.y, w1) FMA4(acc0, x0.z, w2) FMA4(acc0, x0.w, w3)
        FMA4(acc1, x1.x, w0) FMA4(acc1, x1.y, w1) FMA4(acc1, x1.z, w2) FMA4(acc1, x1.w, w3)
        FMA4(acc2, x2.x, w0) FMA4(acc2, x2.y, w1) FMA4(acc2, x2.z, w2) FMA4(acc2, x2.w, w3)
        FMA4(acc3, x3.x, w0) FMA4(acc3, x3.y, w1) FMA4(acc3, x3.z, w2) FMA4(acc3, x3.w, w3)
#undef FMA4
    }
#define EPI(A, i) { \
        int rg = rowbase + r0 + i; \
        if (rg < nrows) { \
            if (RELU) { \
                A.x = A.x > 0.f ? A.x : 0.01f * A.x; \
                A.y = A.y > 0.f ? A.y : 0.01f * A.y; \
                A.z = A.z > 0.f ? A.z : 0.01f * A.z; \
                A.w = A.w > 0.f ? A.w : 0.01f * A.w; \
            } \
            *reinterpret_cast<float4*>(out + (size_t)rg * 64 + c0) = A; \
        } }
    EPI(acc0, 0) EPI(acc1, 1) EPI(acc2, 2) EPI(acc3, 3)
#undef EPI
}

extern "C" void kernel_launch(void* const* d_in, const int* in_sizes, int n_in,
                              void* d_out, int out_size, void* d_ws, size_t ws_size,
                              hipStream_t stream) {
    const float* feat   = (const float*)d_in[0];
    const int*   esrc   = (const int*)d_in[1];
    const int*   edst   = (const int*)d_in[2];
    const int*   labels = (const int*)d_in[3];
    const float* W_lin  = (const float*)d_in[4];
    const float* b_lin  = (const float*)d_in[5];
    const float* W_lin1 = (const float*)d_in[6];
    const float* b_lin1 = (const float*)d_in[7];
    const float* W_th   = (const float*)d_in[8];
    const float* b_th   = (const float*)d_in[9];

    char* ws = (char*)d_ws;
    unsigned short* F[5] = {
        (unsigned short*)(ws + OFF_F0), (unsigned short*)(ws + OFF_F1),
        (unsigned short*)(ws + OFF_F2), (unsigned short*)(ws + OFF_F3),
        (unsigned short*)(ws + OFF_F4)};
    unsigned short* O[4] = {
        (unsigned short*)(ws + OFF_O5), (unsigned short*)(ws + OFF_O6),
        (unsigned short*)(ws + OFF_O7), (unsigned short*)(ws + OFF_O8)};
    unsigned int* csr = (unsigned int*)(ws + OFF_CSR);
    int* rp     = (int*)(ws + OFF_RP);
    unsigned int* cnt = (unsigned int*)(ws + OFF_CNT);
    unsigned long long* cur = (unsigned long long*)(ws + OFF_CUR);
    float* d2o  = (float*)(ws + OFF_D2O);
    float* d2p  = (float*)(ws + OFF_D2P);
    float* d2n  = (float*)(ws + OFF_D2N);
    float* rdo  = (float*)(ws + OFF_RDO);
    float* rdp  = (float*)(ws + OFF_RDP);
    float* rdn  = (float*)(ws + OFF_RDN);
    float* dvo  = (float*)(ws + OFF_DVO);
    float* dvp  = (float*)(ws + OFF_DVP);
    float* dvn  = (float*)(ws + OFF_DVN);
    float* wco  = (float*)(ws + OFF_WCO);
    float* wcpn = (float*)(ws + OFF_WCPN);
    int* part   = (int*)(ws + OFF_PART);

    float* out0 = (float*)d_out;
    float* out1 = out0 + (size_t)N_NODES * 64;
    float* out2 = out1 + (size_t)N_NODES * 64;

    const int EB = N_EDGES / 256;
    const int NB = (N_NODES + 255) / 256;
    const int SB = (N_NODES + 255) / 256 + 1;
    const int HB = N_NODES / 4;               // 1 node per wave64
    const int GB = (N_NODES + 63) / 64;       // 1563 gemm blocks

    hipMemsetAsync(cnt, 0, N_NODES * sizeof(int), stream);
    k_mask_deg<<<EB, 256, 0, stream>>>(esrc, edst, labels, cnt);
    k_dinv<<<NB, 256, 0, stream>>>(cnt, d2o, d2p, d2n, rdo, rdp, rdn, dvo, dvp, dvn);

    k_scan_a<<<SB, 256, 0, stream>>>(cnt, N_NODES, rp, part);
    k_scan_b<<<1, 512, 0, stream>>>(part, SB);
    k_scan_c<<<SB, 256, 0, stream>>>(rp, part, N_NODES, cnt, cur);
    k_fill<<<EB, 256, 0, stream>>>(esrc, edst, labels, cur, csr);

    k_wc_o<<<72, 256, 0, stream>>>(W_lin, wco);
    k_wc_pn<<<80, 256, 0, stream>>>(W_lin1, wcpn);

    k_init<<<N_NODES * 32 / 256, 256, 0, stream>>>(feat, dvo, dvp, dvn, F[0]);

    // fused hops 1..4
    for (int k = 1; k <= 4; ++k)
        k_hop_fused<<<HB, 256, 0, stream>>>(rp, cnt, csr, F[k - 1], F[k], d2o, d2p, d2n);

    // out1: 10 slices (p0..4 from F, n0..4 from F)
    {
        SliceArgs sl;
        for (int k = 0; k < 5; ++k) { sl.ptr[k] = F[k];      sl.stride[k] = 96; }
        for (int k = 0; k < 5; ++k) { sl.ptr[5 + k] = F[k] + 64; sl.stride[5 + k] = 96; }
        k_gemm_fold<10><<<GB, 256, 0, stream>>>(sl, rdp, rdn, 5, wcpn, b_lin1, out1, N_NODES);
    }

    // solo o hops 5..8
    k_hop_o<<<HB, 256, 0, stream>>>(rp, cnt, csr, F[4] + 32, 24, O[0], d2o);
    for (int k = 1; k < 4; ++k)
        k_hop_o<<<HB, 256, 0, stream>>>(rp, cnt, csr, O[k - 1], 8, O[k], d2o);

    // out0: 9 slices (o0..4 from F, o5..8 compact)
    {
        SliceArgs sl;
        for (int k = 0; k < 5; ++k) { sl.ptr[k] = F[k] + 32; sl.stride[k] = 96; }
        for (int k = 0; k < 4; ++k) { sl.ptr[5 + k] = O[k];  sl.stride[5 + k] = 32; }
        sl.ptr[9] = O[0]; sl.stride[9] = 32;   // unused pad
        k_gemm_fold<9><<<GB, 256, 0, stream>>>(sl, rdo, rdo, 9, wco, b_lin, out0, N_NODES);
    }

    // transh
    k_gemm<32, false><<<GB, 256, 0, stream>>>(feat, W_th, b_th, out2, N_NODES);
}

// Round 11
// 703.291 us; speedup vs baseline: 1.3015x; 1.1068x over previous
//
#include <hip/hip_runtime.h>

#define N_NODES 100000
#define N_EDGES 1600000

typedef __attribute__((ext_vector_type(8))) unsigned short ushort8v;

// ---- workspace layout (bytes) ----
// F_k: fused-phase state [N,96] bf16, row = [p(0:32)|o(32:64)|n(64:96)], k=0..4
// O_k: solo-phase o state [N,32] bf16
#define OFF_F0    0UL
#define OFF_F1    19200000UL
#define OFF_F2    38400000UL
#define OFF_F3    57600000UL
#define OFF_F4    76800000UL
#define OFF_O5    96000000UL
#define OFF_O6    102400000UL
#define OFF_O7    108800000UL
#define OFF_O8    115200000UL
#define OFF_CSR   121600000UL    // padded CSR [N][64] u32: p fwd from 0, n bwd from 63
#define OFF_CNT   147200000UL    // packed deg<<16 | posdeg [N] u32
#define OFF_D2O   147700000UL
#define OFF_D2P   148100000UL
#define OFF_D2N   148500000UL
#define OFF_RDO   148900000UL
#define OFF_RDP   149300000UL
#define OFF_RDN   149700000UL
#define OFF_DVO   150100000UL
#define OFF_DVP   150500000UL
#define OFF_DVN   150900000UL
#define OFF_WCO   151300000UL    // folded weights o: [9][32][64] f32
#define OFF_WCPN  151380000UL    // folded weights pn: [10][32][64] f32

__device__ __forceinline__ float bf2f(unsigned short h) {
    union { unsigned u; float f; } c; c.u = ((unsigned)h) << 16; return c.f;
}
__device__ __forceinline__ unsigned short f2bf(float x) {
    union { float f; unsigned u; } c; c.f = x;
    unsigned r = (c.u + 0x7FFFu + ((c.u >> 16) & 1u)) >> 16;
    return (unsigned short)r;
}

__device__ __constant__ float c_TH[4][3] = {
    {0.5f, -0.4f, 0.1f}, {0.25f, 0.5f, -0.25f},
    {0.1f, 0.3f, 0.6f}, {0.05f, -0.2f, 0.8f}};

// ---- single-pass CSR build: count atomic doubles as cursor ----
__global__ __launch_bounds__(256) void k_fill(
    const int* __restrict__ src, const int* __restrict__ dst,
    const int* __restrict__ labels, unsigned int* __restrict__ cnt,
    unsigned int* __restrict__ csr) {
    int e = blockIdx.x * 256 + threadIdx.x;
    int s = src[e], d = dst[e];
    unsigned int p = (labels[s] == labels[d]) ? 1u : 0u;
    unsigned int old = atomicAdd(&cnt[d], 0x10000u + p);
    int slot;
    if (p) slot = (int)(old & 0xFFFF);                              // p: forward
    else   slot = 63 - (int)((old >> 16) - (old & 0xFFFF));         // n: backward
    csr[d * 64 + slot] = (unsigned int)s;
}

__global__ __launch_bounds__(256) void k_dinv(
    const unsigned int* __restrict__ cnt,
    float* __restrict__ d2o, float* __restrict__ d2p, float* __restrict__ d2n,
    float* __restrict__ rdo, float* __restrict__ rdp, float* __restrict__ rdn,
    float* __restrict__ dvo, float* __restrict__ dvp, float* __restrict__ dvn) {
    int v = blockIdx.x * 256 + threadIdx.x;
    if (v >= N_NODES) return;
    unsigned int c = cnt[v];
    int dg = (int)(c >> 16), pg = (int)(c & 0xFFFF), ng = dg - pg;
    float co = (float)max(dg, 1);
    float cp = (float)max(pg, 1);
    float cn = (float)max(ng, 1);
    d2o[v] = 1.f / co; rdo[v] = sqrtf(co); dvo[v] = rsqrtf(co);
    d2p[v] = 1.f / cp; rdp[v] = sqrtf(cp); dvp[v] = rsqrtf(cp);
    d2n[v] = 1.f / cn; rdn[v] = sqrtf(cn); dvn[v] = rsqrtf(cn);
}

// ---- folded-weight precompute ----
__global__ __launch_bounds__(256) void k_wc_o(const float* __restrict__ W, float* __restrict__ Wc) {
    int idx = blockIdx.x * 256 + threadIdx.x;
    if (idx >= 9 * 2048) return;
    int k = idx >> 11, rem = idx & 2047, r = rem >> 6, c = rem & 63;
    float v = 0.f;
#pragma unroll
    for (int j = 0; j < 4; ++j) {
        int m = k - 2 * j;
        if (m >= 0 && m <= 2) v += c_TH[j][m] * W[(32 * j + r) * 64 + c];
    }
    Wc[idx] = v;
}

__global__ __launch_bounds__(256) void k_wc_pn(const float* __restrict__ W1, float* __restrict__ Wc) {
    int idx = blockIdx.x * 256 + threadIdx.x;
    if (idx >= 10 * 2048) return;
    int k5 = idx >> 11, rem = idx & 2047, r = rem >> 6, c = rem & 63;
    float v = 0.f;
    if (k5 < 5) {
#pragma unroll
        for (int j = 0; j < 2; ++j) {
            int m = k5 - 2 * j;
            if (m >= 0 && m <= 2) v += c_TH[j][m] * W1[(32 * j + r) * 64 + c];
        }
    } else {
        int k = k5 - 5;
#pragma unroll
        for (int j = 0; j < 2; ++j) {
            int m = k - 2 * j;
            if (m >= 0 && m <= 2) v += c_TH[2 + j][m] * W1[(32 * (j + 2) + r) * 64 + c];
        }
    }
    Wc[idx] = v;
}

// ---- init: F0 row [p|o|n] = bf16(feat * dv*) ----
__global__ __launch_bounds__(256) void k_init(
    const float* __restrict__ feat,
    const float* __restrict__ dvo, const float* __restrict__ dvp, const float* __restrict__ dvn,
    unsigned short* __restrict__ g0) {
    int idx = blockIdx.x * 256 + threadIdx.x;   // over N*32
    int v = idx >> 5, c = idx & 31;
    float x = feat[idx];
    g0[v * 96 + c]      = f2bf(x * dvp[v]);
    g0[v * 96 + 32 + c] = f2bf(x * dvo[v]);
    g0[v * 96 + 64 + c] = f2bf(x * dvn[v]);
}

// ---- fused hop: o + p + n in one pass over padded CSR rows ----
__global__ __launch_bounds__(256) void k_hop_fused(
    const unsigned int* __restrict__ cnt, const unsigned int* __restrict__ csr,
    const unsigned short* __restrict__ g_old, unsigned short* __restrict__ g_new,
    const float* __restrict__ d2o, const float* __restrict__ d2p, const float* __restrict__ d2n) {
    int v = (blockIdx.x * 256 + threadIdx.x) >> 6;
    int lane = threadIdx.x & 63;
    int slot = lane >> 3, fl = lane & 7;
    unsigned int c = cnt[v];
    int pc = (int)(c & 0xFFFF);
    int nc = (int)(c >> 16) - pc;
    int base = v * 64;
    const ushort8v* gp = reinterpret_cast<const ushort8v*>(g_old);   // 12 units/row
    float a1[8] = {0.f,0.f,0.f,0.f,0.f,0.f,0.f,0.f};  // p-edges window [p|o]
    float a2[8] = {0.f,0.f,0.f,0.f,0.f,0.f,0.f,0.f};  // n-edges window [o|n]
    for (int i = base + slot; i < base + pc; i += 8) {
        int s = (int)csr[i];
        ushort8v h = gp[s * 12 + fl];
#pragma unroll
        for (int j = 0; j < 8; ++j) a1[j] += bf2f(h[j]);
    }
    for (int i = base + 64 - nc + slot; i < base + 64; i += 8) {
        int s = (int)csr[i];
        ushort8v h = gp[s * 12 + 4 + fl];
#pragma unroll
        for (int j = 0; j < 8; ++j) a2[j] += bf2f(h[j]);
    }
#pragma unroll
    for (int m = 8; m < 64; m <<= 1)
#pragma unroll
        for (int j = 0; j < 8; ++j) {
            a1[j] += __shfl_xor(a1[j], m);
            a2[j] += __shfl_xor(a2[j], m);
        }
    float oextra[8];
    int srcl = (lane & 56) | ((fl + 4) & 7);
#pragma unroll
    for (int j = 0; j < 8; ++j) oextra[j] = __shfl(a2[j], srcl);

    if (lane < 4) {                 // p units 0..3
        float dd = d2p[v];
        ushort8v gh = gp[v * 12 + fl];
        ushort8v go;
#pragma unroll
        for (int j = 0; j < 8; ++j) go[j] = f2bf(bf2f(gh[j]) - a1[j] * dd);
        reinterpret_cast<ushort8v*>(g_new)[v * 12 + fl] = go;
    } else if (lane < 8) {          // o units 4..7
        float dd = d2o[v];
        ushort8v gh = gp[v * 12 + fl];
        ushort8v go;
#pragma unroll
        for (int j = 0; j < 8; ++j) go[j] = f2bf(bf2f(gh[j]) - (a1[j] + oextra[j]) * dd);
        reinterpret_cast<ushort8v*>(g_new)[v * 12 + fl] = go;
    } else if (lane >= 12 && lane < 16) {   // n units 8..11
        float dd = d2n[v];
        ushort8v gh = gp[v * 12 + fl + 4];
        ushort8v go;
#pragma unroll
        for (int j = 0; j < 8; ++j) go[j] = f2bf(bf2f(gh[j]) - a2[j] * dd);
        reinterpret_cast<ushort8v*>(g_new)[v * 12 + fl + 4] = go;
    }
}

// ---- solo o-hop: padded CSR, two sections, compact [N,32] output ----
__global__ __launch_bounds__(256) void k_hop_o(
    const unsigned int* __restrict__ cnt, const unsigned int* __restrict__ csr,
    const unsigned short* __restrict__ g_old, int stride_u4,
    unsigned short* __restrict__ g_new, const float* __restrict__ d2) {
    int v = (blockIdx.x * 256 + threadIdx.x) >> 6;
    int lane = threadIdx.x & 63;
    int slot = lane >> 3, fl = lane & 7;
    unsigned int c = cnt[v];
    int pc = (int)(c & 0xFFFF);
    int nc = (int)(c >> 16) - pc;
    int base = v * 64;
    const ushort4* gp = reinterpret_cast<const ushort4*>(g_old);
    float4 acc = make_float4(0.f, 0.f, 0.f, 0.f);
    for (int i = base + slot; i < base + pc; i += 8) {
        int s = (int)csr[i];
        ushort4 h = gp[s * stride_u4 + fl];
        acc.x += bf2f(h.x); acc.y += bf2f(h.y);
        acc.z += bf2f(h.z); acc.w += bf2f(h.w);
    }
    for (int i = base + 64 - nc + slot; i < base + 64; i += 8) {
        int s = (int)csr[i];
        ushort4 h = gp[s * stride_u4 + fl];
        acc.x += bf2f(h.x); acc.y += bf2f(h.y);
        acc.z += bf2f(h.z); acc.w += bf2f(h.w);
    }
#pragma unroll
    for (int m = 8; m < 64; m <<= 1) {
        acc.x += __shfl_xor(acc.x, m);
        acc.y += __shfl_xor(acc.y, m);
        acc.z += __shfl_xor(acc.z, m);
        acc.w += __shfl_xor(acc.w, m);
    }
    if (slot == 0) {
        float dd = d2[v];
        ushort4 gh = gp[v * stride_u4 + fl];
        ushort4 go;
        go.x = f2bf(bf2f(gh.x) - acc.x * dd);
        go.y = f2bf(bf2f(gh.y) - acc.y * dd);
        go.z = f2bf(bf2f(gh.z) - acc.z * dd);
        go.w = f2bf(bf2f(gh.w) - acc.w * dd);
        reinterpret_cast<ushort4*>(g_new)[v * 8 + fl] = go;
    }
}

// ---- folded GEMM: out = leaky(Σ_k (slice_k ⊙ scale) @ Wc_k + b) ----
struct SliceArgs { const unsigned short* ptr[10]; int stride[10]; };

template <int NS>
__global__ __launch_bounds__(256) void k_gemm_fold(
    SliceArgs sl, const float* __restrict__ scA, const float* __restrict__ scB, int nA,
    const float* __restrict__ Wc, const float* __restrict__ bias,
    float* __restrict__ out, int nrows) {
    __shared__ float sX[2][64 * 36];
    __shared__ float sW[2][2048];
    int tid = threadIdx.x;
    int rowbase = blockIdx.x * 64;
    int u = tid & 3, rr = tid >> 2;
    int rgs = rowbase + rr;

#define STAGE(k, b) { \
        float sc = 0.f; ushort8v h = (ushort8v)0; \
        if (rgs < nrows) { \
            sc = ((k) < nA) ? scA[rgs] : scB[rgs]; \
            h = reinterpret_cast<const ushort8v*>(sl.ptr[k] + (size_t)rgs * sl.stride[k])[u]; \
        } \
        float* dx = &sX[b][rr * 36 + u * 8]; \
        _Pragma("unroll") \
        for (int j = 0; j < 8; ++j) dx[j] = bf2f(h[j]) * sc; \
        const float4* wsrc = reinterpret_cast<const float4*>(Wc + (k) * 2048); \
        float4* wdst = reinterpret_cast<float4*>(sW[b]); \
        for (int i = tid; i < 512; i += 256) wdst[i] = wsrc[i]; \
    }

    int c0 = (tid & 15) * 4;
    int r0 = (tid >> 4) * 4;
    float4 acc0 = reinterpret_cast<const float4*>(bias)[tid & 15];
    float4 acc1 = acc0, acc2 = acc0, acc3 = acc0;

    STAGE(0, 0);
    int buf = 0;
    for (int k = 0; k < NS; ++k) {
        __syncthreads();
        if (k + 1 < NS) STAGE(k + 1, buf ^ 1);
        const float* xb = sX[buf];
        const float* wb = sW[buf];
#pragma unroll
        for (int k4 = 0; k4 < 8; ++k4) {
            int kk = k4 * 4;
            float4 x0 = *reinterpret_cast<const float4*>(xb + (r0 + 0) * 36 + kk);
            float4 x1 = *reinterpret_cast<const float4*>(xb + (r0 + 1) * 36 + kk);
            float4 x2 = *reinterpret_cast<const float4*>(xb + (r0 + 2) * 36 + kk);
            float4 x3 = *reinterpret_cast<const float4*>(xb + (r0 + 3) * 36 + kk);
            float4 w0 = *reinterpret_cast<const float4*>(wb + (kk + 0) * 64 + c0);
            float4 w1 = *reinterpret_cast<const float4*>(wb + (kk + 1) * 64 + c0);
            float4 w2 = *reinterpret_cast<const float4*>(wb + (kk + 2) * 64 + c0);
            float4 w3 = *reinterpret_cast<const float4*>(wb + (kk + 3) * 64 + c0);
#define FMA4(A, xs, wv) \
            A.x = fmaf(xs, wv.x, A.x); A.y = fmaf(xs, wv.y, A.y); \
            A.z = fmaf(xs, wv.z, A.z); A.w = fmaf(xs, wv.w, A.w);
            FMA4(acc0, x0.x, w0) FMA4(acc0, x0.y, w1) FMA4(acc0, x0.z, w2) FMA4(acc0, x0.w, w3)
            FMA4(acc1, x1.x, w0) FMA4(acc1, x1.y, w1) FMA4(acc1, x1.z, w2) FMA4(acc1, x1.w, w3)
            FMA4(acc2, x2.x, w0) FMA4(acc2, x2.y, w1) FMA4(acc2, x2.z, w2) FMA4(acc2, x2.w, w3)
            FMA4(acc3, x3.x, w0) FMA4(acc3, x3.y, w1) FMA4(acc3, x3.z, w2) FMA4(acc3, x3.w, w3)
#undef FMA4
        }
        buf ^= 1;
    }
#undef STAGE

#define EPI(A, i) { \
        int rg = rowbase + r0 + i; \
        if (rg < nrows) { \
            A.x = A.x > 0.f ? A.x : 0.01f * A.x; \
            A.y = A.y > 0.f ? A.y : 0.01f * A.y; \
            A.z = A.z > 0.f ? A.z : 0.01f * A.z; \
            A.w = A.w > 0.f ? A.w : 0.01f * A.w; \
            *reinterpret_cast<float4*>(out + (size_t)rg * 64 + c0) = A; \
        } }
    EPI(acc0, 0) EPI(acc1, 1) EPI(acc2, 2) EPI(acc3, 3)
#undef EPI
}

// ---- plain GEMM for transh (K=32, f32 X) ----
template <int KDIM, bool RELU>
__global__ __launch_bounds__(256) void k_gemm(
    const float* __restrict__ X, const float* __restrict__ W,
    const float* __restrict__ bias, float* __restrict__ out, int nrows) {
    constexpr int SXP = KDIM + 4;
    __shared__ float sW[KDIM * 64];
    __shared__ float sX[64 * SXP];
    int tid = threadIdx.x;
    int rowbase = blockIdx.x * 64;
    for (int i = tid; i < KDIM * 16; i += 256)
        reinterpret_cast<float4*>(sW)[i] = reinterpret_cast<const float4*>(W)[i];
    constexpr int QF4 = KDIM / 4;
    constexpr int RPP = 256 / QF4;
    int q = tid & (QF4 - 1);
    int rloc = tid / QF4;
#pragma unroll
    for (int pass = 0; pass < 64 / RPP; ++pass) {
        int r = rloc + pass * RPP;
        int rg = rowbase + r;
        float4 v = make_float4(0.f, 0.f, 0.f, 0.f);
        if (rg < nrows) v = reinterpret_cast<const float4*>(X + (size_t)rg * KDIM)[q];
        float* dst = sX + r * SXP + q * 4;
        dst[0] = v.x; dst[1] = v.y; dst[2] = v.z; dst[3] = v.w;
    }
    __syncthreads();
    int c0 = (tid & 15) * 4;
    int r0 = (tid >> 4) * 4;
    float4 bv = reinterpret_cast<const float4*>(bias)[tid & 15];
    float4 acc0 = bv, acc1 = bv, acc2 = bv, acc3 = bv;
#pragma unroll 4
    for (int k4 = 0; k4 < KDIM / 4; ++k4) {
        int k = k4 * 4;
        float4 x0 = *reinterpret_cast<const float4*>(sX + (r0 + 0) * SXP + k);
        float4 x1 = *reinterpret_cast<const float4*>(sX + (r0 + 1) * SXP + k);
        float4 x2 = *reinterpret_cast<const float4*>(sX + (r0 + 2) * SXP + k);
        float4 x3 = *reinterpret_cast<const float4*>(sX + (r0 + 3) * SXP + k);
        float4 w0 = *reinterpret_cast<const float4*>(sW + (k + 0) * 64 + c0);
        float4 w1 = *reinterpret_cast<const float4*>(sW + (k + 1) * 64 + c0);
        float4 w2 = *reinterpret_cast<const float4*>(sW + (k + 2) * 64 + c0);
        float4 w3 = *reinterpret_cast<const float4*>(sW + (k + 3) * 64 + c0);
#define FMA4(A, xs, wv) \
        A.x = fmaf(xs, wv.x, A.x); A.y = fmaf(xs, wv.y, A.y); \
        A.z = fmaf(xs, wv.z, A.z); A.w = fmaf(xs, wv.w, A.w);
        FMA4(acc0, x0.x, w0) FMA4(acc0, x0.y, w1) FMA4(acc0, x0.z, w2) FMA4(acc0, x0.w, w3)
        FMA4(acc1, x1.x, w0) FMA4(acc1, x1.y, w1) FMA4(acc1, x1.z, w2) FMA4(acc1, x1.w, w3)
        FMA4(acc2, x2.x, w0) FMA4(acc2, x2.y, w1) FMA4(acc2, x2.z, w2) FMA4(acc2, x2.w, w3)
        FMA4(acc3, x3.x, w0) FMA4(acc3, x3.y, w1) FMA4(acc3, x3.z, w2) FMA4(acc3, x3.w, w3)
#undef FMA4
    }
#define EPI(A, i) { \
        int rg = rowbase + r0 + i; \
        if (rg < nrows) { \
            if (RELU) { \
                A.x = A.x > 0.f ? A.x : 0.01f * A.x; \
                A.y = A.y > 0.f ? A.y : 0.01f * A.y; \
                A.z = A.z > 0.f ? A.z : 0.01f * A.z; \
                A.w = A.w > 0.f ? A.w : 0.01f * A.w; \
            } \
            *reinterpret_cast<float4*>(out + (size_t)rg * 64 + c0) = A; \
        } }
    EPI(acc0, 0) EPI(acc1, 1) EPI(acc2, 2) EPI(acc3, 3)
#undef EPI
}

extern "C" void kernel_launch(void* const* d_in, const int* in_sizes, int n_in,
                              void* d_out, int out_size, void* d_ws, size_t ws_size,
                              hipStream_t stream) {
    const float* feat   = (const float*)d_in[0];
    const int*   esrc   = (const int*)d_in[1];
    const int*   edst   = (const int*)d_in[2];
    const int*   labels = (const int*)d_in[3];
    const float* W_lin  = (const float*)d_in[4];
    const float* b_lin  = (const float*)d_in[5];
    const float* W_lin1 = (const float*)d_in[6];
    const float* b_lin1 = (const float*)d_in[7];
    const float* W_th   = (const float*)d_in[8];
    const float* b_th   = (const float*)d_in[9];

    char* ws = (char*)d_ws;
    unsigned short* F[5] = {
        (unsigned short*)(ws + OFF_F0), (unsigned short*)(ws + OFF_F1),
        (unsigned short*)(ws + OFF_F2), (unsigned short*)(ws + OFF_F3),
        (unsigned short*)(ws + OFF_F4)};
    unsigned short* O[4] = {
        (unsigned short*)(ws + OFF_O5), (unsigned short*)(ws + OFF_O6),
        (unsigned short*)(ws + OFF_O7), (unsigned short*)(ws + OFF_O8)};
    unsigned int* csr = (unsigned int*)(ws + OFF_CSR);
    unsigned int* cnt = (unsigned int*)(ws + OFF_CNT);
    float* d2o  = (float*)(ws + OFF_D2O);
    float* d2p  = (float*)(ws + OFF_D2P);
    float* d2n  = (float*)(ws + OFF_D2N);
    float* rdo  = (float*)(ws + OFF_RDO);
    float* rdp  = (float*)(ws + OFF_RDP);
    float* rdn  = (float*)(ws + OFF_RDN);
    float* dvo  = (float*)(ws + OFF_DVO);
    float* dvp  = (float*)(ws + OFF_DVP);
    float* dvn  = (float*)(ws + OFF_DVN);
    float* wco  = (float*)(ws + OFF_WCO);
    float* wcpn = (float*)(ws + OFF_WCPN);

    float* out0 = (float*)d_out;
    float* out1 = out0 + (size_t)N_NODES * 64;
    float* out2 = out1 + (size_t)N_NODES * 64;

    const int EB = N_EDGES / 256;
    const int NB = (N_NODES + 255) / 256;
    const int HB = N_NODES / 4;               // 1 node per wave64
    const int GB = (N_NODES + 63) / 64;

    // single-pass CSR build (count atomic == cursor)
    hipMemsetAsync(cnt, 0, N_NODES * sizeof(int), stream);
    k_fill<<<EB, 256, 0, stream>>>(esrc, edst, labels, cnt, csr);
    k_dinv<<<NB, 256, 0, stream>>>(cnt, d2o, d2p, d2n, rdo, rdp, rdn, dvo, dvp, dvn);

    k_wc_o<<<72, 256, 0, stream>>>(W_lin, wco);
    k_wc_pn<<<80, 256, 0, stream>>>(W_lin1, wcpn);

    k_init<<<N_NODES * 32 / 256, 256, 0, stream>>>(feat, dvo, dvp, dvn, F[0]);

    // fused hops 1..4
    for (int k = 1; k <= 4; ++k)
        k_hop_fused<<<HB, 256, 0, stream>>>(cnt, csr, F[k - 1], F[k], d2o, d2p, d2n);

    // out1: 10 slices (p0..4, n0..4)
    {
        SliceArgs sl;
        for (int k = 0; k < 5; ++k) { sl.ptr[k] = F[k];          sl.stride[k] = 96; }
        for (int k = 0; k < 5; ++k) { sl.ptr[5 + k] = F[k] + 64; sl.stride[5 + k] = 96; }
        k_gemm_fold<10><<<GB, 256, 0, stream>>>(sl, rdp, rdn, 5, wcpn, b_lin1, out1, N_NODES);
    }

    // solo o hops 5..8
    k_hop_o<<<HB, 256, 0, stream>>>(cnt, csr, F[4] + 32, 24, O[0], d2o);
    for (int k = 1; k < 4; ++k)
        k_hop_o<<<HB, 256, 0, stream>>>(cnt, csr, O[k - 1], 8, O[k], d2o);

    // out0: 9 slices (o0..4 from F, o5..8 compact)
    {
        SliceArgs sl;
        for (int k = 0; k < 5; ++k) { sl.ptr[k] = F[k] + 32; sl.stride[k] = 96; }
        for (int k = 0; k < 4; ++k) { sl.ptr[5 + k] = O[k];  sl.stride[5 + k] = 32; }
        sl.ptr[9] = O[0]; sl.stride[9] = 32;   // unused pad
        k_gemm_fold<9><<<GB, 256, 0, stream>>>(sl, rdo, rdo, 9, wco, b_lin, out0, N_NODES);
    }

    // transh
    k_gemm<32, false><<<GB, 256, 0, stream>>>(feat, W_th, b_th, out2, N_NODES);
}